// Round 2
// baseline (2002.838 us; speedup 1.0000x reference)
//
#include <hip/hip_runtime.h>
#include <hip/hip_bf16.h>

// Problem: D=64, H=512, B=2048, S=16, C=256.
// Rows = S*B = 32768 independent samples; 64 sequential AR steps per row.
#define ROWS 32      // rows per block
#define TPB 512      // 8 waves

typedef unsigned short u16;
typedef __attribute__((ext_vector_type(8))) short bf16x8;
typedef __attribute__((ext_vector_type(16))) float f32x16;

// hid_deg[h] = h%63 + 1. Sorted by degree: degrees 1..8 have 9 units, 9..63 have 8.
__device__ __forceinline__ int deg_of_sorted(int i) {
  return (i < 72) ? (i / 9 + 1) : ((i - 8) / 8 + 1);
}
__device__ __forceinline__ int perm_of_sorted(int i) {
  int g, k;
  if (i < 72) { g = i / 9 + 1; k = i % 9; }
  else        { g = (i - 8) / 8 + 1; k = (i - 8) % 8; }
  return (g - 1) + 63 * k;
}
// # hidden units with degree <= d
__device__ __forceinline__ int cum_deg(int d) {
  return (d <= 0) ? 0 : ((d <= 8) ? 9 * d : 8 * d + 8);
}
__device__ __forceinline__ u16 f2bfu(float x) {
  return __builtin_bit_cast(u16, __float2bfloat16(x));
}
__device__ __forceinline__ unsigned pkbf2(float a, float b) {
  return (unsigned)f2bfu(a) | ((unsigned)f2bfu(b) << 16);
}
__device__ __forceinline__ float bf2f(u16 u) {
  return __builtin_bit_cast(float, ((unsigned)u) << 16);
}
__device__ __forceinline__ float softplus_f(float x) {
  return fmaxf(x, 0.f) + log1pf(expf(-fabsf(x)));
}

// ---------------- prep: permuted/masked weights ----------------
// mw2f layout: [(k>>3)][n(512)][k&7] bf16 -> one bf16x8 per (kblock8, n): MFMA B-frag friendly.
__global__ __launch_bounds__(256) void prep_w(
    const float* __restrict__ W1, const float* __restrict__ W2,
    const float* __restrict__ b2, const float* __restrict__ W3,
    float* __restrict__ mw1s, u16* __restrict__ mw2f,
    float* __restrict__ mw3t, float* __restrict__ b2s) {
  int idx = blockIdx.x * 256 + threadIdx.x;
  if (idx < 262144) {  // MW2 sorted+masked, fragment layout
    int kb = idx >> 12, n = (idx >> 3) & 511, kk = idx & 7;
    int k = kb * 8 + kk;
    float v = (deg_of_sorted(k) <= deg_of_sorted(n))
                  ? W2[perm_of_sorted(k) * 512 + perm_of_sorted(n)] : 0.f;
    mw2f[idx] = f2bfu(v);
    return;
  }
  idx -= 262144;
  if (idx < 32768) {   // MW1 sorted+masked (rows d, cols sorted j), fp32
    int d = idx >> 9, j = idx & 511;
    mw1s[idx] = (deg_of_sorted(j) >= d + 1) ? W1[d * 512 + perm_of_sorted(j)] : 0.f;
    return;
  }
  idx -= 32768;
  if (idx < 65536) {   // MW3 transposed: [out col c(128)][sorted j(512)], fp32
    int c = idx >> 9, j = idx & 511;
    mw3t[idx] = (deg_of_sorted(j) <= (c & 63)) ? W3[perm_of_sorted(j) * 128 + c] : 0.f;
    return;
  }
  idx -= 65536;
  if (idx < 512) b2s[idx] = b2[perm_of_sorted(idx)];
}

// ctx_proj[b][sorted j] = context[b] @ Wc[:, perm(j)] + b1[perm(j)], fp32
__global__ __launch_bounds__(256) void prep_ctx(
    const float* __restrict__ context, const float* __restrict__ Wc,
    const float* __restrict__ b1, float* __restrict__ ctxp) {
  __shared__ float cs[256];
  const int b = blockIdx.x;
  const int j = blockIdx.y * 256 + threadIdx.x;
  cs[threadIdx.x] = context[b * 256 + threadIdx.x];
  __syncthreads();
  const int pj = perm_of_sorted(j);
  float acc = b1[pj];
  #pragma unroll 4
  for (int c = 0; c < 256; ++c) acc += cs[c] * Wc[c * 512 + pj];
  ctxp[b * 512 + j] = acc;
}

// ---------------- main: 64 AR steps, 32 rows per block ----------------
__global__ __launch_bounds__(TPB) void made_main(
    const float* __restrict__ eps, const float* __restrict__ b3,
    const float* __restrict__ ctxp, const float* __restrict__ mw1s,
    const float* __restrict__ mw3t, const float* __restrict__ b2s,
    const u16* __restrict__ mw2f, float* __restrict__ out) {
  constexpr int A1S = 516;  // a1 row stride (floats), padded: conflict-free
  __shared__ __align__(16) float a1[ROWS * A1S];    // 66048 B  pre-activation (fp32)
  __shared__ __align__(16) u16   h1s[ROWS * 512];   // 32768 B  relu(a1) bf16, XOR-swizzled
  __shared__ __align__(16) u16   h2s[512 * 36];     // 36864 B  [col][row padded 36]
  __shared__ __align__(16) float zb[ROWS * 64];     //  8192 B  z samples
  __shared__ __align__(16) float part[8][2][32];    //  2048 B  layer-3 partials

  const int tid  = threadIdx.x;
  const int lane = tid & 63;
  const int wave = tid >> 6;
  const int g0   = blockIdx.x * ROWS;       // first global row (s,b)-flat
  const int b0   = g0 & 2047;               // context row base (g = s*2048 + b)

  // init a1 = ctx_proj (broadcast over s)
  for (int idx = tid; idx < ROWS * 512; idx += TPB) {
    int r = idx >> 9, j = idx & 511;
    a1[r * A1S + j] = ctxp[(b0 + r) * 512 + j];
  }
  __syncthreads();

  const int m    = lane & 31;   // MFMA row (= output row within block) / B col
  const int kq   = lane >> 5;   // k-half selector
  const int xorm = m & 7;       // h1 LDS XOR swizzle key
  const u16* bLane = mw2f + ((kq * 512 + m) << 3);

  for (int d = 0; d < 64; ++d) {
    const int Cd = cum_deg(d);            // active h2 prefix
    const int nt = (Cd + 31) >> 5;        // active 32-col N-tiles
    int Kmax = 0;
    if (nt > 0) Kmax = (cum_deg(deg_of_sorted(nt * 32 - 1)) + 15) & ~15;

    // Phase A0: h1 = bf16(relu(a1)) for k < Kmax, 4-elem chunks, XOR-swizzled blocks
    #pragma unroll
    for (int i = 0; i < (ROWS * 128) / TPB; ++i) {
      int c  = tid + i * TPB;
      int kc = c & 127;
      int k  = kc << 2;
      if (k < Kmax) {
        int r = c >> 7;
        const float4 v = *(const float4*)&a1[r * A1S + k];
        uint2 uu;
        uu.x = pkbf2(fmaxf(v.x, 0.f), fmaxf(v.y, 0.f));
        uu.y = pkbf2(fmaxf(v.z, 0.f), fmaxf(v.w, 0.f));
        int e = r * 512 + ((((kc >> 1) ^ (r & 7))) << 3) + ((kc & 1) << 2);
        *(uint2*)&h1s[e] = uu;
      }
    }
    __syncthreads();

    // Phase A: layer-2 MFMA (32x32x16 bf16), N restricted to prefix, K block-triangular
    for (int jt = wave; jt < nt; jt += 8) {
      const int kend   = cum_deg(deg_of_sorted(jt * 32 + 31));
      const int ksteps = (kend + 15) >> 4;
      f32x16 acc;
      #pragma unroll
      for (int i = 0; i < 16; ++i) acc[i] = 0.f;
      const u16* bp  = bLane + jt * 256;
      const u16* h1m = h1s + m * 512;
      for (int ks = 0; ks < ksteps; ++ks) {
        int blk = (ks * 2 + kq) ^ xorm;
        bf16x8 af = *(const bf16x8*)(h1m + blk * 8);
        bf16x8 bf = *(const bf16x8*)(bp + ks * 8192);
        acc = __builtin_amdgcn_mfma_f32_32x32x16_bf16(af, bf, acc, 0, 0, 0);
      }
      const int col  = jt * 32 + m;
      const float bias = b2s[col];
      #pragma unroll
      for (int g2 = 0; g2 < 4; ++g2) {  // C row = (reg&3) + 8*(reg>>2) + 4*kq
        uint2 hv;
        hv.x = pkbf2(fmaxf(acc[g2 * 4 + 0] + bias, 0.f),
                     fmaxf(acc[g2 * 4 + 1] + bias, 0.f));
        hv.y = pkbf2(fmaxf(acc[g2 * 4 + 2] + bias, 0.f),
                     fmaxf(acc[g2 * 4 + 3] + bias, 0.f));
        *(uint2*)&h2s[col * 36 + g2 * 8 + kq * 4] = hv;
      }
    }
    __syncthreads();

    // Phase B: layer-3 partial dots (only cols d and 64+d of out)
    {
      const int r    = lane & 31;
      const int half = lane >> 5;
      const float* w3row = mw3t + (half * 64 + d) * 512;
      float acc0 = 0.f, acc1 = 0.f;
      for (int j = wave; j < Cd; j += 16) {
        acc0 += bf2f(h2s[j * 36 + r]) * w3row[j];
        int j2 = j + 8;
        if (j2 < Cd) acc1 += bf2f(h2s[j2 * 36 + r]) * w3row[j2];
      }
      part[wave][half][r] = acc0 + acc1;
    }
    __syncthreads();

    // Phase B2: reduce, softplus, sample; store mu/scale
    if (tid < 64) {
      const int r    = lane & 31;
      const int half = lane >> 5;
      float v = 0.f;
      #pragma unroll
      for (int q = 0; q < 8; ++q) v += part[q][half][r];
      v += b3[half * 64 + d];
      float other = __shfl_xor(v, 32);
      if (half == 0) {
        float mu = v;
        float sc = softplus_f(other);
        float e  = eps[(g0 + r) * 64 + d];
        float z  = fmaf(sc, e, mu);
        zb[r * 64 + d] = z;
        out[2097152 + (g0 + r) * 64 + d] = mu;
        out[4194304 + (g0 + r) * 64 + d] = sc;
      }
    }
    __syncthreads();

    // Phase C: a1 rank-1 update over suffix j >= Cd (MW1 row d support)
    {
      int j = Cd + tid;
      if (j < 512) {
        float w = mw1s[d * 512 + j];
        #pragma unroll
        for (int r = 0; r < ROWS; ++r)
          a1[r * A1S + j] += zb[r * 64 + d] * w;
      }
    }
    __syncthreads();
  }

  // final coalesced z write (one float4 per thread)
  {
    int r = tid >> 4, c4 = tid & 15;
    *(float4*)&out[(g0 + r) * 64 + c4 * 4] = *(const float4*)&zb[r * 64 + c4 * 4];
  }
}

extern "C" void kernel_launch(void* const* d_in, const int* in_sizes, int n_in,
                              void* d_out, int out_size, void* d_ws, size_t ws_size,
                              hipStream_t stream) {
  (void)in_sizes; (void)n_in; (void)out_size; (void)ws_size;
  const float* context = (const float*)d_in[0];
  const float* eps     = (const float*)d_in[1];
  const float* W1      = (const float*)d_in[2];
  const float* Wc      = (const float*)d_in[3];
  const float* b1      = (const float*)d_in[4];
  const float* W2      = (const float*)d_in[5];
  const float* b2      = (const float*)d_in[6];
  const float* W3      = (const float*)d_in[7];
  const float* b3      = (const float*)d_in[8];
  float* out = (float*)d_out;

  // workspace layout (floats): ctxp[2048*512] | mw1s[64*512] | mw3t[128*512] | b2s[512] | mw2f(u16)[512*512]
  float* ws   = (float*)d_ws;
  float* ctxp = ws;
  float* mw1s = ctxp + 2048 * 512;
  float* mw3t = mw1s + 64 * 512;
  float* b2s  = mw3t + 128 * 512;
  u16*   mw2f = (u16*)(b2s + 512);   // total ~4.9 MB

  prep_w<<<1410, 256, 0, stream>>>(W1, W2, b2, W3, mw1s, mw2f, mw3t, b2s);
  prep_ctx<<<dim3(2048, 2), 256, 0, stream>>>(context, Wc, b1, ctxp);
  made_main<<<1024, TPB, 0, stream>>>(eps, b3, ctxp, mw1s, mw3t, b2s, mw2f, out);
}

// Round 3
// 1906.314 us; speedup vs baseline: 1.0506x; 1.0506x over previous
//
#include <hip/hip_runtime.h>
#include <hip/hip_bf16.h>

// D=64, H=512, B=2048, S=16, C=256. Rows = 32768 independent samples, 64 AR steps.
#define ROWS 32      // rows per block
#define TPB 256      // 4 waves

typedef unsigned short u16;
typedef __attribute__((ext_vector_type(8))) short bf16x8;
typedef __attribute__((ext_vector_type(16))) float f32x16;

__device__ __forceinline__ int deg_of_sorted(int i) {
  return (i < 72) ? (i / 9 + 1) : ((i - 8) / 8 + 1);
}
__device__ __forceinline__ int perm_of_sorted(int i) {
  int g, k;
  if (i < 72) { g = i / 9 + 1; k = i % 9; }
  else        { g = (i - 8) / 8 + 1; k = (i - 8) % 8; }
  return (g - 1) + 63 * k;
}
__device__ __forceinline__ int cum_deg(int d) {
  return (d <= 0) ? 0 : ((d <= 8) ? 9 * d : 8 * d + 8);
}
__device__ __forceinline__ u16 f2bfu(float x) {
  return __builtin_bit_cast(u16, __float2bfloat16(x));
}
__device__ __forceinline__ unsigned pkbf2(float a, float b) {
  return (unsigned)f2bfu(a) | ((unsigned)f2bfu(b) << 16);
}
__device__ __forceinline__ float bf2f(u16 u) {
  return __builtin_bit_cast(float, ((unsigned)u) << 16);
}
__device__ __forceinline__ float softplus_f(float x) {
  return fmaxf(x, 0.f) + log1pf(expf(-fabsf(x)));
}

// ---------------- prep kernels (unchanged from R2, correctness-proven) ----------------
__global__ __launch_bounds__(256) void prep_w(
    const float* __restrict__ W1, const float* __restrict__ W2,
    const float* __restrict__ b2, const float* __restrict__ W3,
    float* __restrict__ mw1s, u16* __restrict__ mw2f,
    float* __restrict__ mw3t, float* __restrict__ b2s) {
  int idx = blockIdx.x * 256 + threadIdx.x;
  if (idx < 262144) {  // MW2 sorted+masked, MFMA-B fragment layout [(k>>3)][n][k&7]
    int kb = idx >> 12, n = (idx >> 3) & 511, kk = idx & 7;
    int k = kb * 8 + kk;
    float v = (deg_of_sorted(k) <= deg_of_sorted(n))
                  ? W2[perm_of_sorted(k) * 512 + perm_of_sorted(n)] : 0.f;
    mw2f[idx] = f2bfu(v);
    return;
  }
  idx -= 262144;
  if (idx < 32768) {   // MW1 sorted+masked rows d, cols sorted j
    int d = idx >> 9, j = idx & 511;
    mw1s[idx] = (deg_of_sorted(j) >= d + 1) ? W1[d * 512 + perm_of_sorted(j)] : 0.f;
    return;
  }
  idx -= 32768;
  if (idx < 65536) {   // MW3 transposed [out col c][sorted j]
    int c = idx >> 9, j = idx & 511;
    mw3t[idx] = (deg_of_sorted(j) <= (c & 63)) ? W3[perm_of_sorted(j) * 128 + c] : 0.f;
    return;
  }
  idx -= 65536;
  if (idx < 512) b2s[idx] = b2[perm_of_sorted(idx)];
}

__global__ __launch_bounds__(256) void prep_ctx(
    const float* __restrict__ context, const float* __restrict__ Wc,
    const float* __restrict__ b1, float* __restrict__ ctxp) {
  __shared__ float cs[256];
  const int b = blockIdx.x;
  const int j = blockIdx.y * 256 + threadIdx.x;
  cs[threadIdx.x] = context[b * 256 + threadIdx.x];
  __syncthreads();
  const int pj = perm_of_sorted(j);
  float acc = b1[pj];
  #pragma unroll 4
  for (int c = 0; c < 256; ++c) acc += cs[c] * Wc[c * 512 + pj];
  ctxp[b * 512 + j] = acc;
}

// ---------------- main: a1 in registers, incremental h1 conversion ----------------
__global__ __launch_bounds__(TPB, 2) void made_main(
    const float* __restrict__ eps, const float* __restrict__ b3,
    const float* __restrict__ ctxp, const float* __restrict__ mw1s,
    const float* __restrict__ mw3t, const float* __restrict__ b2s,
    const u16* __restrict__ mw2f, float* __restrict__ out) {
  __shared__ __align__(16) u16   h1s[ROWS * 512];   // 32 KB bf16 relu(a1), XOR-swizzled
  __shared__ __align__(16) u16   h2s[512 * 36];     // 36 KB [col][row pad36]
  __shared__ __align__(16) float zb[ROWS * 64];     //  8 KB
  __shared__ __align__(16) float part[4][2][32];    //  1 KB

  const int tid  = threadIdx.x;
  const int lane = tid & 63;
  const int wave = tid >> 6;               // 0..3
  const int g0   = blockIdx.x * ROWS;
  const int b0   = g0 & 2047;

  // a1 ownership: row rA = tid&31, cols [jA, jA+64)
  const int rA = tid & 31;
  const int jA = (tid >> 5) << 6;
  float a1r[64];
  #pragma unroll
  for (int i = 0; i < 64; ++i) a1r[i] = ctxp[(b0 + rA) * 512 + jA + i];

  // zero h1s once: beyond-frozen reads must be exactly 0
  #pragma unroll
  for (int i = 0; i < 8; ++i) {
    *(uint4*)&h1s[(tid + i * TPB) * 8] = uint4{0, 0, 0, 0};
  }
  __syncthreads();

  const int m    = lane & 31;    // MFMA A row / B col
  const int kq   = lane >> 5;    // k-half
  const int xorm = m & 7;        // h1 swizzle key
  const u16* bLane = mw2f + ((kq * 512 + m) << 3);
  const int r3   = lane & 31;    // phase-B row
  const int half = lane >> 5;    // phase-B mu/scale selector

  for (int d = 0; d < 64; ++d) {
    const int Cd = cum_deg(d);
    const int nt = (Cd + 31) >> 5;
    const int KmaxA = (Cd + 15) & ~15;

    // Phase A: layer-2 MFMA (32x32x16), K capped at align16(Cd), 4-deep pipelined B loads
    for (int jt = wave; jt < nt; jt += 4) {
      int kend = cum_deg(deg_of_sorted(jt * 32 + 31));
      if (kend > KmaxA) kend = KmaxA;
      const int ksteps = (kend + 15) >> 4;
      f32x16 acc;
      #pragma unroll
      for (int i = 0; i < 16; ++i) acc[i] = 0.f;
      const u16* bp  = bLane + jt * 256;
      const u16* h1m = h1s + m * 512;
      int ks = 0;
      for (; ks + 4 <= ksteps; ks += 4) {
        bf16x8 bf0 = *(const bf16x8*)(bp + (ks + 0) * 8192);
        bf16x8 bf1 = *(const bf16x8*)(bp + (ks + 1) * 8192);
        bf16x8 bf2 = *(const bf16x8*)(bp + (ks + 2) * 8192);
        bf16x8 bf3 = *(const bf16x8*)(bp + (ks + 3) * 8192);
        bf16x8 af0 = *(const bf16x8*)(h1m + (((((ks + 0) * 2 + kq)) ^ xorm) << 3));
        bf16x8 af1 = *(const bf16x8*)(h1m + (((((ks + 1) * 2 + kq)) ^ xorm) << 3));
        bf16x8 af2 = *(const bf16x8*)(h1m + (((((ks + 2) * 2 + kq)) ^ xorm) << 3));
        bf16x8 af3 = *(const bf16x8*)(h1m + (((((ks + 3) * 2 + kq)) ^ xorm) << 3));
        acc = __builtin_amdgcn_mfma_f32_32x32x16_bf16(af0, bf0, acc, 0, 0, 0);
        acc = __builtin_amdgcn_mfma_f32_32x32x16_bf16(af1, bf1, acc, 0, 0, 0);
        acc = __builtin_amdgcn_mfma_f32_32x32x16_bf16(af2, bf2, acc, 0, 0, 0);
        acc = __builtin_amdgcn_mfma_f32_32x32x16_bf16(af3, bf3, acc, 0, 0, 0);
      }
      for (; ks < ksteps; ++ks) {
        bf16x8 bf = *(const bf16x8*)(bp + ks * 8192);
        bf16x8 af = *(const bf16x8*)(h1m + ((((ks * 2 + kq)) ^ xorm) << 3));
        acc = __builtin_amdgcn_mfma_f32_32x32x16_bf16(af, bf, acc, 0, 0, 0);
      }
      const int col = jt * 32 + m;
      const float bias = b2s[col];
      #pragma unroll
      for (int g2 = 0; g2 < 4; ++g2) {  // C row = (reg&3) + 8*(reg>>2) + 4*kq
        uint2 hv;
        hv.x = pkbf2(fmaxf(acc[g2 * 4 + 0] + bias, 0.f),
                     fmaxf(acc[g2 * 4 + 1] + bias, 0.f));
        hv.y = pkbf2(fmaxf(acc[g2 * 4 + 2] + bias, 0.f),
                     fmaxf(acc[g2 * 4 + 3] + bias, 0.f));
        *(uint2*)&h2s[col * 36 + g2 * 8 + kq * 4] = hv;
      }
    }
    __syncthreads();

    // Phase B: layer-3 partial dots for out cols d and 64+d
    {
      const float* w3row = mw3t + (half * 64 + d) * 512;
      float acc0 = 0.f, acc1 = 0.f;
      for (int j = wave; j < Cd; j += 8) {
        acc0 += bf2f(h2s[j * 36 + r3]) * w3row[j];
        int j2 = j + 4;
        if (j2 < Cd) acc1 += bf2f(h2s[j2 * 36 + r3]) * w3row[j2];
      }
      part[wave][half][r3] = acc0 + acc1;
    }
    __syncthreads();

    // Phase B2: reduce, softplus, sample
    if (tid < 64) {
      const int r = tid & 31;
      const int hf = tid >> 5;
      float v = part[0][hf][r] + part[1][hf][r] + part[2][hf][r] + part[3][hf][r];
      v += b3[hf * 64 + d];
      float other = __shfl_xor(v, 32);
      if (hf == 0) {
        float mu = v;
        float sc = softplus_f(other);
        float e  = eps[(g0 + r) * 64 + d];
        float z  = fmaf(sc, e, mu);
        zb[r * 64 + d] = z;
        out[2097152 + (g0 + r) * 64 + d] = mu;
        out[4194304 + (g0 + r) * 64 + d] = sc;
      }
    }
    __syncthreads();

    // Phase C: rank-1 update of owned a1 slice + incremental h1 conversion
    {
      const int Cnext = cum_deg(d + 1);
      const float z = zb[rA * 64 + d];
      if (jA + 63 >= Cd) {
        const float* w1d = mw1s + d * 512;
        #pragma unroll
        for (int i = 0; i < 64; ++i) {
          int j = jA + i;
          if (j >= Cd) a1r[i] += z * w1d[j];
        }
      }
      if (jA < Cnext && jA + 64 > Cd) {
        #pragma unroll
        for (int i = 0; i < 64; ++i) {
          int j = jA + i;
          if (j >= Cd && j < Cnext && j < 512) {
            h1s[rA * 512 + ((((j >> 3) ^ (rA & 7)) << 3) | (j & 7))] =
                f2bfu(fmaxf(a1r[i], 0.f));
          }
        }
      }
    }
    __syncthreads();
  }

  // final z write: 2 float4 per thread
  {
    int r = tid >> 3, c = (tid & 7) * 8;
    *(float4*)&out[(g0 + r) * 64 + c]     = *(const float4*)&zb[r * 64 + c];
    *(float4*)&out[(g0 + r) * 64 + c + 4] = *(const float4*)&zb[r * 64 + c + 4];
  }
}

extern "C" void kernel_launch(void* const* d_in, const int* in_sizes, int n_in,
                              void* d_out, int out_size, void* d_ws, size_t ws_size,
                              hipStream_t stream) {
  (void)in_sizes; (void)n_in; (void)out_size; (void)ws_size;
  const float* context = (const float*)d_in[0];
  const float* eps     = (const float*)d_in[1];
  const float* W1      = (const float*)d_in[2];
  const float* Wc      = (const float*)d_in[3];
  const float* b1      = (const float*)d_in[4];
  const float* W2      = (const float*)d_in[5];
  const float* b2      = (const float*)d_in[6];
  const float* W3      = (const float*)d_in[7];
  const float* b3      = (const float*)d_in[8];
  float* out = (float*)d_out;

  float* ws   = (float*)d_ws;
  float* ctxp = ws;
  float* mw1s = ctxp + 2048 * 512;
  float* mw3t = mw1s + 64 * 512;
  float* b2s  = mw3t + 128 * 512;
  u16*   mw2f = (u16*)(b2s + 512);

  prep_w<<<1410, 256, 0, stream>>>(W1, W2, b2, W3, mw1s, mw2f, mw3t, b2s);
  prep_ctx<<<dim3(2048, 2), 256, 0, stream>>>(context, Wc, b1, ctxp);
  made_main<<<1024, TPB, 0, stream>>>(eps, b3, ctxp, mw1s, mw3t, b2s, mw2f, out);
}

// Round 4
// 1556.735 us; speedup vs baseline: 1.2866x; 1.2246x over previous
//
#include <hip/hip_runtime.h>
#include <hip/hip_bf16.h>

// D=64, H=512, B=2048, S=16, C=256. Rows = 32768 independent samples, 64 AR steps.
#define ROWS 32      // rows per block
#define TPB 256      // 4 waves

typedef unsigned short u16;
typedef __attribute__((ext_vector_type(8))) short bf16x8;
typedef __attribute__((ext_vector_type(16))) float f32x16;

__device__ __forceinline__ int deg_of_sorted(int i) {
  return (i < 72) ? (i / 9 + 1) : ((i - 8) / 8 + 1);
}
__device__ __forceinline__ int perm_of_sorted(int i) {
  int g, k;
  if (i < 72) { g = i / 9 + 1; k = i % 9; }
  else        { g = (i - 8) / 8 + 1; k = (i - 8) % 8; }
  return (g - 1) + 63 * k;
}
__device__ __forceinline__ int cum_deg(int d) {
  return (d <= 0) ? 0 : ((d <= 8) ? 9 * d : 8 * d + 8);
}
__device__ __forceinline__ u16 f2bfu(float x) {
  return __builtin_bit_cast(u16, __float2bfloat16(x));
}
__device__ __forceinline__ unsigned pkbf2(float a, float b) {
  return (unsigned)f2bfu(a) | ((unsigned)f2bfu(b) << 16);
}
__device__ __forceinline__ float bf2f(u16 u) {
  return __builtin_bit_cast(float, ((unsigned)u) << 16);
}
__device__ __forceinline__ float softplus_f(float x) {
  return fmaxf(x, 0.f) + log1pf(expf(-fabsf(x)));
}

// ---------------- prep: permuted/masked weights ----------------
__global__ __launch_bounds__(256) void prep_w(
    const float* __restrict__ W1, const float* __restrict__ W2,
    const float* __restrict__ b2, const float* __restrict__ W3,
    float* __restrict__ mw1s, u16* __restrict__ mw2f,
    u16* __restrict__ mw3b, float* __restrict__ b2s) {
  int idx = blockIdx.x * 256 + threadIdx.x;
  if (idx < 262144) {  // MW2 sorted+masked, MFMA-B fragment layout [(k>>3)][n][k&7]
    int kb = idx >> 12, n = (idx >> 3) & 511, kk = idx & 7;
    int k = kb * 8 + kk;
    float v = (deg_of_sorted(k) <= deg_of_sorted(n))
                  ? W2[perm_of_sorted(k) * 512 + perm_of_sorted(n)] : 0.f;
    mw2f[idx] = f2bfu(v);
    return;
  }
  idx -= 262144;
  if (idx < 32768) {   // MW1 sorted+masked rows d, cols sorted j (f32)
    int d = idx >> 9, j = idx & 511;
    mw1s[idx] = (deg_of_sorted(j) >= d + 1) ? W1[d * 512 + perm_of_sorted(j)] : 0.f;
    return;
  }
  idx -= 32768;
  if (idx < 65536) {   // MW3 transposed bf16: [out col c(128)][sorted j(512)]
    int c = idx >> 9, j = idx & 511;
    float v = (deg_of_sorted(j) <= (c & 63)) ? W3[perm_of_sorted(j) * 128 + c] : 0.f;
    mw3b[idx] = f2bfu(v);
    return;
  }
  idx -= 65536;
  if (idx < 512) b2s[idx] = b2[perm_of_sorted(idx)];
}

__global__ __launch_bounds__(256) void prep_ctx(
    const float* __restrict__ context, const float* __restrict__ Wc,
    const float* __restrict__ b1, float* __restrict__ ctxp) {
  __shared__ float cs[256];
  const int b = blockIdx.x;
  const int j = blockIdx.y * 256 + threadIdx.x;
  cs[threadIdx.x] = context[b * 256 + threadIdx.x];
  __syncthreads();
  const int pj = perm_of_sorted(j);
  float acc = b1[pj];
  #pragma unroll 4
  for (int c = 0; c < 256; ++c) acc += cs[c] * Wc[c * 512 + pj];
  ctxp[b * 512 + j] = acc;
}

// ---------------- main ----------------
__global__ __launch_bounds__(TPB, 2) void made_main(
    const float* __restrict__ eps, const float* __restrict__ b3,
    const float* __restrict__ ctxp, const float* __restrict__ mw1s,
    const u16* __restrict__ mw3b, const float* __restrict__ b2s,
    const u16* __restrict__ mw2f, float* __restrict__ out) {
  __shared__ __align__(16) u16   h1s[ROWS * 512];   // 32768 B bf16 relu(a1), XOR-swizzled
  __shared__ __align__(16) u16   h2s[512 * 36];     // 36864 B [col][row pad36]
  __shared__ __align__(16) float part[4][2][32];    //  1024 B layer-3 partials
  __shared__ __align__(16) u16   w3s[2 * 512];      //  2048 B staged w3 rows (d, 64+d)
  __shared__ __align__(16) float w1s[512];          //  2048 B staged w1 row d
  __shared__ __align__(16) float b3s[128];          //   512 B

  const int tid  = threadIdx.x;
  const int lane = tid & 63;
  const int wave = tid >> 6;               // 0..3
  const int g0   = blockIdx.x * ROWS;
  const int b0   = g0 & 2047;

  // a1 ownership: row rA = tid&31, cols [jA, jA+64)
  const int rA = tid & 31;
  const int jA = (tid >> 5) << 6;
  float a1r[64];
  #pragma unroll
  for (int i = 0; i < 64; ++i) a1r[i] = ctxp[(b0 + rA) * 512 + jA + i];

  // zero h1s (beyond-frozen reads must be exactly 0); preload b3
  #pragma unroll
  for (int i = 0; i < 8; ++i) {
    *(uint4*)&h1s[(tid + i * TPB) * 8] = uint4{0, 0, 0, 0};
  }
  if (tid < 128) b3s[tid] = b3[tid];
  __syncthreads();

  const int m    = lane & 31;    // MFMA A row / B col
  const int kq   = lane >> 5;    // k-half
  const int xorm = m & 7;        // h1 swizzle key
  const u16* bLane = mw2f + ((kq * 512 + m) << 3);
  const int r3   = lane & 31;
  const int half = lane >> 5;

  for (int d = 0; d < 64; ++d) {
    const int Cd = cum_deg(d);
    const int nt = (Cd + 31) >> 5;
    const int KmaxA = (Cd + 15) & ~15;

    // --- stage-issue: w3 rows (d, 64+d) bf16 + w1 row d f32 -> regs (write to LDS later)
    uint4 stg;
    if (tid < 64)        stg = *(const uint4*)&mw3b[d * 512 + tid * 8];
    else if (tid < 128)  stg = *(const uint4*)&mw3b[(64 + d) * 512 + (tid - 64) * 8];
    else                 stg = *(const uint4*)&mw1s[d * 512 + (tid - 128) * 4];

    // Phase A: layer-2 MFMA (32x32x16), K capped at align16(Cd)
    for (int jt = wave; jt < nt; jt += 4) {
      int kend = cum_deg(deg_of_sorted(jt * 32 + 31));
      if (kend > KmaxA) kend = KmaxA;
      const int ksteps = (kend + 15) >> 4;
      f32x16 acc;
      #pragma unroll
      for (int i = 0; i < 16; ++i) acc[i] = 0.f;
      const u16* bp  = bLane + jt * 256;
      const u16* h1m = h1s + m * 512;
      int ks = 0;
      for (; ks + 4 <= ksteps; ks += 4) {
        bf16x8 bf0 = *(const bf16x8*)(bp + (ks + 0) * 8192);
        bf16x8 bf1 = *(const bf16x8*)(bp + (ks + 1) * 8192);
        bf16x8 bf2 = *(const bf16x8*)(bp + (ks + 2) * 8192);
        bf16x8 bf3 = *(const bf16x8*)(bp + (ks + 3) * 8192);
        bf16x8 af0 = *(const bf16x8*)(h1m + (((((ks + 0) * 2 + kq)) ^ xorm) << 3));
        bf16x8 af1 = *(const bf16x8*)(h1m + (((((ks + 1) * 2 + kq)) ^ xorm) << 3));
        bf16x8 af2 = *(const bf16x8*)(h1m + (((((ks + 2) * 2 + kq)) ^ xorm) << 3));
        bf16x8 af3 = *(const bf16x8*)(h1m + (((((ks + 3) * 2 + kq)) ^ xorm) << 3));
        acc = __builtin_amdgcn_mfma_f32_32x32x16_bf16(af0, bf0, acc, 0, 0, 0);
        acc = __builtin_amdgcn_mfma_f32_32x32x16_bf16(af1, bf1, acc, 0, 0, 0);
        acc = __builtin_amdgcn_mfma_f32_32x32x16_bf16(af2, bf2, acc, 0, 0, 0);
        acc = __builtin_amdgcn_mfma_f32_32x32x16_bf16(af3, bf3, acc, 0, 0, 0);
      }
      for (; ks < ksteps; ++ks) {
        bf16x8 bf = *(const bf16x8*)(bp + ks * 8192);
        bf16x8 af = *(const bf16x8*)(h1m + ((((ks * 2 + kq)) ^ xorm) << 3));
        acc = __builtin_amdgcn_mfma_f32_32x32x16_bf16(af, bf, acc, 0, 0, 0);
      }
      const int col = jt * 32 + m;
      const float bias = b2s[col];
      #pragma unroll
      for (int g2 = 0; g2 < 4; ++g2) {  // C row = (reg&3) + 8*(reg>>2) + 4*kq
        uint2 hv;
        hv.x = pkbf2(fmaxf(acc[g2 * 4 + 0] + bias, 0.f),
                     fmaxf(acc[g2 * 4 + 1] + bias, 0.f));
        hv.y = pkbf2(fmaxf(acc[g2 * 4 + 2] + bias, 0.f),
                     fmaxf(acc[g2 * 4 + 3] + bias, 0.f));
        *(uint2*)&h2s[col * 36 + g2 * 8 + kq * 4] = hv;
      }
    }
    // --- stage-write: dump staged w3/w1 into LDS (latency was hidden under phase A)
    if (tid < 128) *(uint4*)&w3s[tid * 8] = stg;
    else           *(uint4*)&w1s[(tid - 128) * 4] = stg;
    __syncthreads();

    // Phase B: layer-3 partial dots for out cols d and 64+d (w3 from LDS, broadcast)
    {
      const u16* w3row = w3s + half * 512;
      float acc0 = 0.f, acc1 = 0.f;
      for (int j = wave; j < Cd; j += 8) {
        acc0 += bf2f(h2s[j * 36 + r3]) * bf2f(w3row[j]);
        int j2 = j + 4;
        if (j2 < Cd) acc1 += bf2f(h2s[j2 * 36 + r3]) * bf2f(w3row[j2]);
      }
      part[wave][half][r3] = acc0 + acc1;
    }
    __syncthreads();

    // Phase B2 (replicated in all waves): reduce, softplus, sample -> lane-local z
    float z;
    {
      float v = part[0][half][r3] + part[1][half][r3] +
                part[2][half][r3] + part[3][half][r3] + b3s[half * 64 + d];
      float other = __shfl_xor(v, 32);
      float mu = half ? other : v;
      float sc = softplus_f(half ? v : other);
      float e  = eps[(g0 + r3) * 64 + d];
      z = fmaf(sc, e, mu);
      if (wave == 0 && half == 0) {
        out[(g0 + r3) * 64 + d]           = z;
        out[2097152 + (g0 + r3) * 64 + d] = mu;
        out[4194304 + (g0 + r3) * 64 + d] = sc;
      }
    }

    // Phase C: rank-1 update of owned a1 slice + incremental h1 conversion (w1 from LDS)
    {
      const int Cnext = cum_deg(d + 1);
      if (jA + 63 >= Cd) {
        #pragma unroll
        for (int i = 0; i < 64; ++i) {
          int j = jA + i;
          if (j >= Cd) a1r[i] += z * w1s[j];
        }
      }
      if (jA < Cnext && jA + 64 > Cd) {
        #pragma unroll
        for (int i = 0; i < 64; ++i) {
          int j = jA + i;
          if (j >= Cd && j < Cnext && j < 512) {
            h1s[rA * 512 + ((((j >> 3) ^ (rA & 7)) << 3) | (j & 7))] =
                f2bfu(fmaxf(a1r[i], 0.f));
          }
        }
      }
    }
    __syncthreads();
  }
}

extern "C" void kernel_launch(void* const* d_in, const int* in_sizes, int n_in,
                              void* d_out, int out_size, void* d_ws, size_t ws_size,
                              hipStream_t stream) {
  (void)in_sizes; (void)n_in; (void)out_size; (void)ws_size;
  const float* context = (const float*)d_in[0];
  const float* eps     = (const float*)d_in[1];
  const float* W1      = (const float*)d_in[2];
  const float* Wc      = (const float*)d_in[3];
  const float* b1      = (const float*)d_in[4];
  const float* W2      = (const float*)d_in[5];
  const float* b2      = (const float*)d_in[6];
  const float* W3      = (const float*)d_in[7];
  const float* b3      = (const float*)d_in[8];
  float* out = (float*)d_out;

  // ws: ctxp f32[2048*512] | mw1s f32[64*512] | b2s f32[512] | mw2f u16[262144] | mw3b u16[65536]
  float* ws   = (float*)d_ws;
  float* ctxp = ws;
  float* mw1s = ctxp + 2048 * 512;
  float* b2s  = mw1s + 64 * 512;
  u16*   mw2f = (u16*)(b2s + 512);
  u16*   mw3b = mw2f + 262144;

  prep_w<<<1410, 256, 0, stream>>>(W1, W2, b2, W3, mw1s, mw2f, mw3b, b2s);
  prep_ctx<<<dim3(2048, 2), 256, 0, stream>>>(context, Wc, b1, ctxp);
  made_main<<<1024, TPB, 0, stream>>>(eps, b3, ctxp, mw1s, mw3b, b2s, mw2f, out);
}

// Round 5
// 1472.477 us; speedup vs baseline: 1.3602x; 1.0572x over previous
//
#include <hip/hip_runtime.h>
#include <hip/hip_bf16.h>

// D=64, H=512, B=2048, S=16, C=256. Rows = 32768 independent samples, 64 AR steps.
#define ROWS 32      // rows per block
#define TPB 512      // 8 waves

typedef unsigned short u16;
typedef __attribute__((ext_vector_type(8))) short bf16x8;
typedef __attribute__((ext_vector_type(16))) float f32x16;

__device__ __forceinline__ int deg_of_sorted(int i) {
  return (i < 72) ? (i / 9 + 1) : ((i - 8) / 8 + 1);
}
__device__ __forceinline__ int perm_of_sorted(int i) {
  int g, k;
  if (i < 72) { g = i / 9 + 1; k = i % 9; }
  else        { g = (i - 8) / 8 + 1; k = (i - 8) % 8; }
  return (g - 1) + 63 * k;
}
__device__ __forceinline__ int cum_deg(int d) {
  return (d <= 0) ? 0 : ((d <= 8) ? 9 * d : 8 * d + 8);
}
__device__ __forceinline__ u16 f2bfu(float x) {
  return __builtin_bit_cast(u16, __float2bfloat16(x));
}
__device__ __forceinline__ float bf2f(u16 u) {
  return __builtin_bit_cast(float, ((unsigned)u) << 16);
}
__device__ __forceinline__ float softplus_f(float x) {
  return fmaxf(x, 0.f) + log1pf(expf(-fabsf(x)));
}

// ---------------- prep: permuted/masked weights (unchanged, proven) ----------------
__global__ __launch_bounds__(256) void prep_w(
    const float* __restrict__ W1, const float* __restrict__ W2,
    const float* __restrict__ b2, const float* __restrict__ W3,
    float* __restrict__ mw1s, u16* __restrict__ mw2f,
    u16* __restrict__ mw3b, float* __restrict__ b2s) {
  int idx = blockIdx.x * 256 + threadIdx.x;
  if (idx < 262144) {  // MW2 sorted+masked, MFMA-B fragment layout [(k>>3)][n][k&7]
    int kb = idx >> 12, n = (idx >> 3) & 511, kk = idx & 7;
    int k = kb * 8 + kk;
    float v = (deg_of_sorted(k) <= deg_of_sorted(n))
                  ? W2[perm_of_sorted(k) * 512 + perm_of_sorted(n)] : 0.f;
    mw2f[idx] = f2bfu(v);
    return;
  }
  idx -= 262144;
  if (idx < 32768) {   // MW1 sorted+masked rows d, cols sorted j (f32)
    int d = idx >> 9, j = idx & 511;
    mw1s[idx] = (deg_of_sorted(j) >= d + 1) ? W1[d * 512 + perm_of_sorted(j)] : 0.f;
    return;
  }
  idx -= 32768;
  if (idx < 65536) {   // MW3 transposed bf16: [out col c(128)][sorted j(512)]
    int c = idx >> 9, j = idx & 511;
    float v = (deg_of_sorted(j) <= (c & 63)) ? W3[perm_of_sorted(j) * 128 + c] : 0.f;
    mw3b[idx] = f2bfu(v);
    return;
  }
  idx -= 65536;
  if (idx < 512) b2s[idx] = b2[perm_of_sorted(idx)];
}

__global__ __launch_bounds__(256) void prep_ctx(
    const float* __restrict__ context, const float* __restrict__ Wc,
    const float* __restrict__ b1, float* __restrict__ ctxp) {
  __shared__ float cs[256];
  const int b = blockIdx.x;
  const int j = blockIdx.y * 256 + threadIdx.x;
  cs[threadIdx.x] = context[b * 256 + threadIdx.x];
  __syncthreads();
  const int pj = perm_of_sorted(j);
  float acc = b1[pj];
  #pragma unroll 4
  for (int c = 0; c < 256; ++c) acc += cs[c] * Wc[c * 512 + pj];
  ctxp[b * 512 + j] = acc;
}

// ---------------- main: h2 register-resident, reduce-scatter phase B ----------------
__global__ __launch_bounds__(TPB, 2) void made_main(
    const float* __restrict__ eps, const float* __restrict__ b3,
    const float* __restrict__ ctxp, const float* __restrict__ mw1s,
    const u16* __restrict__ mw3b, const float* __restrict__ b2s,
    const u16* __restrict__ mw2f, float* __restrict__ out) {
  __shared__ __align__(16) u16   h1s[ROWS * 512];   // 32768 B bf16 relu(a1), XOR-swizzled
  __shared__ __align__(16) float part[8][64];       //  2048 B per-wave (row,out) sums
  __shared__ __align__(16) float w1s[512];          //  2048 B staged w1 row d
  __shared__ __align__(16) float b3s[128];          //   512 B
  __shared__ __align__(16) float epsb[32];          //   128 B staged eps column d

  const int tid  = threadIdx.x;
  const int lane = tid & 63;
  const int wave = tid >> 6;               // 0..7
  const int g0   = blockIdx.x * ROWS;
  const int b0   = g0 & 2047;

  // a1 ownership: row rA = tid&31, cols [jA, jA+32)
  const int rA = tid & 31;
  const int jA = (tid >> 5) << 5;
  float a1r[32];
  #pragma unroll
  for (int t = 0; t < 8; ++t) {
    *(float4*)&a1r[t * 4] = *(const float4*)&ctxp[(b0 + rA) * 512 + jA + t * 4];
  }

  // zero h1s (beyond-frozen reads must be exactly 0); preload b3
  #pragma unroll
  for (int i = 0; i < 4; ++i) {
    *(uint4*)&h1s[(tid + i * TPB) * 8] = uint4{0, 0, 0, 0};
  }
  if (tid < 128) b3s[tid] = b3[tid];
  __syncthreads();

  const int m    = lane & 31;    // MFMA A row / B col-within-tile
  const int kq   = lane >> 5;    // k-half / output half in B2
  const int xorm = m & 7;        // h1 swizzle key
  const int jt0  = wave;         // this wave's two N-tiles (balanced pairing)
  const int jt1  = 15 - wave;
  const u16* bLane = mw2f + ((kq * 512 + m) << 3);
  const float b2v0 = b2s[jt0 * 32 + m];
  const float b2v1 = b2s[jt1 * 32 + m];
  // reduce-scatter final (out,row) owned by this lane: i = bitrev5(m)
  const int outIdx = m & 1;
  const int rowIdx = ((m & 2) << 3) | ((m & 4) << 1) | ((m & 8) >> 2) |
                     ((m & 16) >> 4) | (kq << 2);

  // register-resident h2 accumulators (stale tiles neutralized by mw3b mask zeros)
  f32x16 acc0, acc1;
  #pragma unroll
  for (int i = 0; i < 16; ++i) { acc0[i] = 0.f; acc1[i] = 0.f; }

  for (int d = 0; d < 64; ++d) {
    const int Cd = cum_deg(d);
    const int Cnext = cum_deg(d + 1);
    const int nt = (Cd + 31) >> 5;
    const int KmaxA = (Cd + 15) & ~15;

    // --- stage-issue (consumed after phase A): w3 scalars, w1 row, eps column
    const float w3v00 = bf2f(mw3b[d * 512 + jt0 * 32 + m]);
    const float w3v01 = bf2f(mw3b[d * 512 + jt1 * 32 + m]);
    const float w3v10 = bf2f(mw3b[(64 + d) * 512 + jt0 * 32 + m]);
    const float w3v11 = bf2f(mw3b[(64 + d) * 512 + jt1 * 32 + m]);
    float4 w1stg;
    if (tid < 128) w1stg = *(const float4*)&mw1s[d * 512 + tid * 4];
    float epsstg;
    if (tid < 32) epsstg = eps[(g0 + tid) * 64 + d];

    // --- Phase A: layer-2 MFMA into register acc (2 tiles per wave)
    auto run_tile = [&](int jt, f32x16& acc) {
      int kend = cum_deg(deg_of_sorted(jt * 32 + 31));
      if (kend > KmaxA) kend = KmaxA;
      const int ksteps = (kend + 15) >> 4;
      #pragma unroll
      for (int i = 0; i < 16; ++i) acc[i] = 0.f;
      const u16* bp  = bLane + jt * 256;
      const u16* h1m = h1s + m * 512;
      int ks = 0;
      for (; ks + 4 <= ksteps; ks += 4) {
        bf16x8 bf0 = *(const bf16x8*)(bp + (ks + 0) * 8192);
        bf16x8 bf1 = *(const bf16x8*)(bp + (ks + 1) * 8192);
        bf16x8 bf2 = *(const bf16x8*)(bp + (ks + 2) * 8192);
        bf16x8 bf3 = *(const bf16x8*)(bp + (ks + 3) * 8192);
        bf16x8 af0 = *(const bf16x8*)(h1m + (((((ks + 0) * 2 + kq)) ^ xorm) << 3));
        bf16x8 af1 = *(const bf16x8*)(h1m + (((((ks + 1) * 2 + kq)) ^ xorm) << 3));
        bf16x8 af2 = *(const bf16x8*)(h1m + (((((ks + 2) * 2 + kq)) ^ xorm) << 3));
        bf16x8 af3 = *(const bf16x8*)(h1m + (((((ks + 3) * 2 + kq)) ^ xorm) << 3));
        acc = __builtin_amdgcn_mfma_f32_32x32x16_bf16(af0, bf0, acc, 0, 0, 0);
        acc = __builtin_amdgcn_mfma_f32_32x32x16_bf16(af1, bf1, acc, 0, 0, 0);
        acc = __builtin_amdgcn_mfma_f32_32x32x16_bf16(af2, bf2, acc, 0, 0, 0);
        acc = __builtin_amdgcn_mfma_f32_32x32x16_bf16(af3, bf3, acc, 0, 0, 0);
      }
      for (; ks < ksteps; ++ks) {
        bf16x8 bf = *(const bf16x8*)(bp + ks * 8192);
        bf16x8 af = *(const bf16x8*)(h1m + ((((ks * 2 + kq)) ^ xorm) << 3));
        acc = __builtin_amdgcn_mfma_f32_32x32x16_bf16(af, bf, acc, 0, 0, 0);
      }
    };
    if (jt0 < nt) run_tile(jt0, acc0);
    if (jt1 < nt) run_tile(jt1, acc1);

    // --- stage-write (latency hidden under phase A)
    if (tid < 128) *(float4*)&w1s[tid * 4] = w1stg;
    if (tid < 32) epsb[tid] = epsstg;
    __syncthreads();

    // --- Phase B: per-lane partials from register h2, then reduce-scatter over m
    float v[32];
    #pragma unroll
    for (int i = 0; i < 16; ++i) {
      float h20 = fmaxf(acc0[i] + b2v0, 0.f);
      float h21 = fmaxf(acc1[i] + b2v1, 0.f);
      v[i]      = h20 * w3v00 + h21 * w3v01;
      v[16 + i] = h20 * w3v10 + h21 * w3v11;
    }
    {
      const bool s1 = (m & 1);
      #pragma unroll
      for (int j = 0; j < 16; ++j) {
        float snd = s1 ? v[j] : v[j + 16];
        float got = __shfl_xor(snd, 1);
        v[j] = (s1 ? v[j + 16] : v[j]) + got;
      }
      const bool s2 = (m & 2);
      #pragma unroll
      for (int j = 0; j < 8; ++j) {
        float snd = s2 ? v[j] : v[j + 8];
        float got = __shfl_xor(snd, 2);
        v[j] = (s2 ? v[j + 8] : v[j]) + got;
      }
      const bool s4 = (m & 4);
      #pragma unroll
      for (int j = 0; j < 4; ++j) {
        float snd = s4 ? v[j] : v[j + 4];
        float got = __shfl_xor(snd, 4);
        v[j] = (s4 ? v[j + 4] : v[j]) + got;
      }
      const bool s8 = (m & 8);
      #pragma unroll
      for (int j = 0; j < 2; ++j) {
        float snd = s8 ? v[j] : v[j + 2];
        float got = __shfl_xor(snd, 8);
        v[j] = (s8 ? v[j + 2] : v[j]) + got;
      }
      const bool s16 = (m & 16);
      {
        float snd = s16 ? v[0] : v[1];
        float got = __shfl_xor(snd, 16);
        v[0] = (s16 ? v[1] : v[0]) + got;
      }
    }
    part[wave][outIdx * 32 + rowIdx] = v[0];
    __syncthreads();

    // --- Phase B2 (replicated all waves): cross-wave sum, softplus, sample
    float z;
    {
      const int r3 = m;  // lane&31
      float s = b3s[kq * 64 + d];
      #pragma unroll
      for (int w = 0; w < 8; ++w) s += part[w][kq * 32 + r3];
      float other = __shfl_xor(s, 32);
      float mu = kq ? other : s;
      float sc = softplus_f(kq ? s : other);
      z = fmaf(sc, epsb[r3], mu);
      if (tid < 32) {
        out[(g0 + r3) * 64 + d]           = z;
        out[2097152 + (g0 + r3) * 64 + d] = mu;
        out[4194304 + (g0 + r3) * 64 + d] = sc;
      }
    }

    // --- Phase C: rank-1 a1 update on owned slice + incremental h1 freeze
    if (jA + 31 >= Cd) {
      #pragma unroll
      for (int i = 0; i < 32; ++i) {
        int j = jA + i;
        if (j >= Cd) a1r[i] += z * w1s[j];
      }
      if (jA < Cnext) {
        #pragma unroll
        for (int i = 0; i < 32; ++i) {
          int j = jA + i;
          if (j >= Cd && j < Cnext) {
            h1s[rA * 512 + ((((j >> 3) ^ (rA & 7)) << 3) | (j & 7))] =
                f2bfu(fmaxf(a1r[i], 0.f));
          }
        }
      }
    }
    __syncthreads();
  }
}

extern "C" void kernel_launch(void* const* d_in, const int* in_sizes, int n_in,
                              void* d_out, int out_size, void* d_ws, size_t ws_size,
                              hipStream_t stream) {
  (void)in_sizes; (void)n_in; (void)out_size; (void)ws_size;
  const float* context = (const float*)d_in[0];
  const float* eps     = (const float*)d_in[1];
  const float* W1      = (const float*)d_in[2];
  const float* Wc      = (const float*)d_in[3];
  const float* b1      = (const float*)d_in[4];
  const float* W2      = (const float*)d_in[5];
  const float* b2      = (const float*)d_in[6];
  const float* W3      = (const float*)d_in[7];
  const float* b3      = (const float*)d_in[8];
  float* out = (float*)d_out;

  // ws: ctxp f32[2048*512] | mw1s f32[64*512] | b2s f32[512] | mw2f u16[262144] | mw3b u16[65536]
  float* ws   = (float*)d_ws;
  float* ctxp = ws;
  float* mw1s = ctxp + 2048 * 512;
  float* b2s  = mw1s + 64 * 512;
  u16*   mw2f = (u16*)(b2s + 512);
  u16*   mw3b = mw2f + 262144;

  prep_w<<<1410, 256, 0, stream>>>(W1, W2, b2, W3, mw1s, mw2f, mw3b, b2s);
  prep_ctx<<<dim3(2048, 2), 256, 0, stream>>>(context, Wc, b1, ctxp);
  made_main<<<1024, TPB, 0, stream>>>(eps, b3, ctxp, mw1s, mw3b, b2s, mw2f, out);
}

// Round 8
// 1340.149 us; speedup vs baseline: 1.4945x; 1.0987x over previous
//
#include <hip/hip_runtime.h>
#include <hip/hip_bf16.h>

// D=64, H=512, B=2048, S=16, C=256. Rows = 32768 independent samples, 64 AR steps.
#define ROWS 64      // rows per block
#define TPB 1024     // 16 waves

typedef unsigned short u16;
typedef __attribute__((ext_vector_type(8))) short bf16x8;
typedef __attribute__((ext_vector_type(16))) float f32x16;

__device__ __forceinline__ int deg_of_sorted(int i) {
  return (i < 72) ? (i / 9 + 1) : ((i - 8) / 8 + 1);
}
__device__ __forceinline__ int perm_of_sorted(int i) {
  int g, k;
  if (i < 72) { g = i / 9 + 1; k = i % 9; }
  else        { g = (i - 8) / 8 + 1; k = (i - 8) % 8; }
  return (g - 1) + 63 * k;
}
__device__ __forceinline__ int cum_deg(int d) {
  return (d <= 0) ? 0 : ((d <= 8) ? 9 * d : 8 * d + 8);
}
__device__ __forceinline__ u16 f2bfu(float x) {
  return __builtin_bit_cast(u16, __float2bfloat16(x));
}
__device__ __forceinline__ float bf2f(u16 u) {
  return __builtin_bit_cast(float, ((unsigned)u) << 16);
}
__device__ __forceinline__ float softplus_f(float x) {
  return fmaxf(x, 0.f) + log1pf(expf(-fabsf(x)));
}

// ---------------- prep: permuted/masked weights (unchanged, proven) ----------------
__global__ __launch_bounds__(256) void prep_w(
    const float* __restrict__ W1, const float* __restrict__ W2,
    const float* __restrict__ b2, const float* __restrict__ W3,
    float* __restrict__ mw1s, u16* __restrict__ mw2f,
    u16* __restrict__ mw3b, float* __restrict__ b2s) {
  int idx = blockIdx.x * 256 + threadIdx.x;
  if (idx < 262144) {  // MW2 sorted+masked, MFMA-B fragment layout [(k>>3)][n][k&7]
    int kb = idx >> 12, n = (idx >> 3) & 511, kk = idx & 7;
    int k = kb * 8 + kk;
    float v = (deg_of_sorted(k) <= deg_of_sorted(n))
                  ? W2[perm_of_sorted(k) * 512 + perm_of_sorted(n)] : 0.f;
    mw2f[idx] = f2bfu(v);
    return;
  }
  idx -= 262144;
  if (idx < 32768) {   // MW1 sorted+masked rows d, cols sorted j (f32)
    int d = idx >> 9, j = idx & 511;
    mw1s[idx] = (deg_of_sorted(j) >= d + 1) ? W1[d * 512 + perm_of_sorted(j)] : 0.f;
    return;
  }
  idx -= 32768;
  if (idx < 65536) {   // MW3 transposed bf16: [out col c(128)][sorted j(512)]
    int c = idx >> 9, j = idx & 511;
    float v = (deg_of_sorted(j) <= (c & 63)) ? W3[perm_of_sorted(j) * 128 + c] : 0.f;
    mw3b[idx] = f2bfu(v);
    return;
  }
  idx -= 65536;
  if (idx < 512) b2s[idx] = b2[perm_of_sorted(idx)];
}

__global__ __launch_bounds__(256) void prep_ctx(
    const float* __restrict__ context, const float* __restrict__ Wc,
    const float* __restrict__ b1, float* __restrict__ ctxp) {
  __shared__ float cs[256];
  const int b = blockIdx.x;
  const int j = blockIdx.y * 256 + threadIdx.x;
  cs[threadIdx.x] = context[b * 256 + threadIdx.x];
  __syncthreads();
  const int pj = perm_of_sorted(j);
  float acc = b1[pj];
  #pragma unroll 4
  for (int c = 0; c < 256; ++c) acc += cs[c] * Wc[c * 512 + pj];
  ctxp[b * 512 + j] = acc;
}

// ---------------- main: 64 rows/block, 16 waves, M=64 per B-fragment ----------------
__global__ __launch_bounds__(TPB, 4) void made_main(
    const float* __restrict__ eps, const float* __restrict__ b3,
    const float* __restrict__ ctxp, const float* __restrict__ mw1s,
    const u16* __restrict__ mw3b, const float* __restrict__ b2s,
    const u16* __restrict__ mw2f, float* __restrict__ out) {
  __shared__ __align__(16) u16   h1s[ROWS * 512];   // 65536 B bf16 relu(a1), XOR-swizzled (key=row&31)
  __shared__ __align__(16) float part2[128 * 17];   //  8704 B (out,row) x wave partials, stride 17
  __shared__ __align__(16) float w1s[512];          //  2048 B staged w1 row d
  __shared__ __align__(16) float b3s[128];          //   512 B
  __shared__ __align__(16) float epsb[64];          //   256 B staged eps column d

  const int tid  = threadIdx.x;
  const int lane = tid & 63;
  const int wave = tid >> 6;               // 0..15
  const int g0   = blockIdx.x * ROWS;
  const int b0   = g0 & 2047;

  // a1 ownership: row rA = lane (0..63), cols [jA, jA+32) with jA = wave*32
  const int rA = lane;
  const int jA = wave * 32;
  float a1r[32];
  #pragma unroll
  for (int t = 0; t < 8; ++t) {
    *(float4*)&a1r[t * 4] = *(const float4*)&ctxp[(b0 + rA) * 512 + jA + t * 4];
  }

  // zero h1s (beyond-frozen reads must be exactly 0); preload b3
  #pragma unroll
  for (int i = 0; i < 4; ++i) {
    *(uint4*)&h1s[(tid + i * TPB) * 8] = uint4{0, 0, 0, 0};
  }
  if (tid < 128) b3s[tid] = b3[tid];
  __syncthreads();

  const int m  = lane & 31;    // MFMA A row within half / B col-within-tile
  const int kq = lane >> 5;    // k-half
  const int jt = wave;         // this wave's N-tile (0..15)
  const u16* bLane = mw2f + ((kq * 512 + m) << 3);
  const u16* bp    = bLane + jt * 256;
  const float b2v  = b2s[jt * 32 + m];
  const u16* h1m0  = h1s + m * 512;          // rows 0..31 (swizzle key m)
  const u16* h1m1  = h1s + (32 + m) * 512;   // rows 32..63 (swizzle key m)
  // butterfly output ownership: (out = m&1, rowIdx in 0..31)
  const int oi = m & 1;
  const int rowIdx = ((m & 2) << 3) | ((m & 4) << 1) | ((m & 8) >> 2) |
                     ((m & 16) >> 4) | (kq << 2);

  f32x16 acc0, acc1;
  #pragma unroll
  for (int i = 0; i < 16; ++i) { acc0[i] = 0.f; acc1[i] = 0.f; }

  // per-lane butterfly reduce-scatter over 32 values (16 cols x 2 outs)
  auto butterfly = [&](const f32x16& acc, float w3v0, float w3v1) -> float {
    float v[32];
    #pragma unroll
    for (int i = 0; i < 16; ++i) {
      float h2 = fmaxf(acc[i] + b2v, 0.f);
      v[i]      = h2 * w3v0;
      v[16 + i] = h2 * w3v1;
    }
    const bool s1 = (m & 1);
    #pragma unroll
    for (int j = 0; j < 16; ++j) {
      float snd = s1 ? v[j] : v[j + 16];
      float got = __shfl_xor(snd, 1);
      v[j] = (s1 ? v[j + 16] : v[j]) + got;
    }
    const bool s2 = (m & 2);
    #pragma unroll
    for (int j = 0; j < 8; ++j) {
      float snd = s2 ? v[j] : v[j + 8];
      float got = __shfl_xor(snd, 2);
      v[j] = (s2 ? v[j + 8] : v[j]) + got;
    }
    const bool s4 = (m & 4);
    #pragma unroll
    for (int j = 0; j < 4; ++j) {
      float snd = s4 ? v[j] : v[j + 4];
      float got = __shfl_xor(snd, 4);
      v[j] = (s4 ? v[j + 4] : v[j]) + got;
    }
    const bool s8 = (m & 8);
    #pragma unroll
    for (int j = 0; j < 2; ++j) {
      float snd = s8 ? v[j] : v[j + 2];
      float got = __shfl_xor(snd, 8);
      v[j] = (s8 ? v[j + 2] : v[j]) + got;
    }
    const bool s16 = (m & 16);
    float snd = s16 ? v[0] : v[1];
    float got = __shfl_xor(snd, 16);
    return (s16 ? v[1] : v[0]) + got;
  };

  for (int d = 0; d < 64; ++d) {
    const int Cd    = cum_deg(d);
    const int Cnext = cum_deg(d + 1);
    const int nt    = (Cd + 31) >> 5;
    const int KmaxA = (Cd + 15) & ~15;

    // --- stage-issue (consumed after phase A)
    const float w3v0 = bf2f(mw3b[d * 512 + jt * 32 + m]);
    const float w3v1 = bf2f(mw3b[(64 + d) * 512 + jt * 32 + m]);
    float4 w1stg;
    if (tid < 128) w1stg = *(const float4*)&mw1s[d * 512 + tid * 4];
    float epsstg;
    if (tid < 64) epsstg = eps[(g0 + tid) * 64 + d];

    // --- Phase A: layer-2 MFMA, one N-tile, both M-halves share the B-fragment
    if (jt < nt) {
      int kend = cum_deg(deg_of_sorted(jt * 32 + 31));
      if (kend > KmaxA) kend = KmaxA;
      const int ksteps = (kend + 15) >> 4;
      #pragma unroll
      for (int i = 0; i < 16; ++i) { acc0[i] = 0.f; acc1[i] = 0.f; }
      int ks = 0;
      for (; ks + 2 <= ksteps; ks += 2) {
        bf16x8 bfA  = *(const bf16x8*)(bp + (ks + 0) * 8192);
        bf16x8 bfB  = *(const bf16x8*)(bp + (ks + 1) * 8192);
        bf16x8 a00  = *(const bf16x8*)(h1m0 + ((((2 * ks + 0 + kq)) ^ m) << 3));
        bf16x8 a01  = *(const bf16x8*)(h1m1 + ((((2 * ks + 0 + kq)) ^ m) << 3));
        bf16x8 a10  = *(const bf16x8*)(h1m0 + ((((2 * ks + 2 + kq)) ^ m) << 3));
        bf16x8 a11  = *(const bf16x8*)(h1m1 + ((((2 * ks + 2 + kq)) ^ m) << 3));
        acc0 = __builtin_amdgcn_mfma_f32_32x32x16_bf16(a00, bfA, acc0, 0, 0, 0);
        acc1 = __builtin_amdgcn_mfma_f32_32x32x16_bf16(a01, bfA, acc1, 0, 0, 0);
        acc0 = __builtin_amdgcn_mfma_f32_32x32x16_bf16(a10, bfB, acc0, 0, 0, 0);
        acc1 = __builtin_amdgcn_mfma_f32_32x32x16_bf16(a11, bfB, acc1, 0, 0, 0);
      }
      for (; ks < ksteps; ++ks) {
        bf16x8 bfA = *(const bf16x8*)(bp + ks * 8192);
        bf16x8 a00 = *(const bf16x8*)(h1m0 + ((((2 * ks + kq)) ^ m) << 3));
        bf16x8 a01 = *(const bf16x8*)(h1m1 + ((((2 * ks + kq)) ^ m) << 3));
        acc0 = __builtin_amdgcn_mfma_f32_32x32x16_bf16(a00, bfA, acc0, 0, 0, 0);
        acc1 = __builtin_amdgcn_mfma_f32_32x32x16_bf16(a01, bfA, acc1, 0, 0, 0);
      }
    }

    // --- Phase B (register-only): butterflies -> per-lane partials
    float p0 = butterfly(acc0, w3v0, w3v1);
    float p1 = butterfly(acc1, w3v0, w3v1);
    part2[(oi * 64 + rowIdx) * 17 + wave]      = p0;
    part2[(oi * 64 + 32 + rowIdx) * 17 + wave] = p1;

    // --- stage-write (latency hidden under phase A/B)
    if (tid < 128) *(float4*)&w1s[tid * 4] = w1stg;
    if (tid < 64) epsb[tid] = epsstg;
    __syncthreads();

    // --- B2 (replicated): cross-wave sums, softplus, sample
    float msum = b3s[d], ssum = b3s[64 + d];
    #pragma unroll
    for (int w = 0; w < 16; ++w) {
      msum += part2[rA * 17 + w];
      ssum += part2[(64 + rA) * 17 + w];
    }
    const float mu = msum;
    const float sc = softplus_f(ssum);
    const float z  = fmaf(sc, epsb[rA], mu);
    if (tid < 64) {
      out[(g0 + rA) * 64 + d]           = z;
      out[2097152 + (g0 + rA) * 64 + d] = mu;
      out[4194304 + (g0 + rA) * 64 + d] = sc;
    }

    // --- Phase C: rank-1 a1 update on owned slice + incremental h1 freeze
    if (jA + 31 >= Cd) {
      #pragma unroll
      for (int i = 0; i < 32; ++i) {
        int j = jA + i;
        if (j >= Cd) a1r[i] += z * w1s[j];
      }
      if (jA < Cnext) {
        #pragma unroll
        for (int i = 0; i < 32; ++i) {
          int j = jA + i;
          if (j >= Cd && j < Cnext) {
            h1s[rA * 512 + (((((j >> 3) ^ (rA & 31))) << 3) | (j & 7))] =
                f2bfu(fmaxf(a1r[i], 0.f));
          }
        }
      }
    }
    __syncthreads();
  }
}

extern "C" void kernel_launch(void* const* d_in, const int* in_sizes, int n_in,
                              void* d_out, int out_size, void* d_ws, size_t ws_size,
                              hipStream_t stream) {
  (void)in_sizes; (void)n_in; (void)out_size; (void)ws_size;
  const float* context = (const float*)d_in[0];
  const float* eps     = (const float*)d_in[1];
  const float* W1      = (const float*)d_in[2];
  const float* Wc      = (const float*)d_in[3];
  const float* b1      = (const float*)d_in[4];
  const float* W2      = (const float*)d_in[5];
  const float* b2      = (const float*)d_in[6];
  const float* W3      = (const float*)d_in[7];
  const float* b3      = (const float*)d_in[8];
  float* out = (float*)d_out;

  // ws: ctxp f32[2048*512] | mw1s f32[64*512] | b2s f32[512] | mw2f u16[262144] | mw3b u16[65536]
  float* ws   = (float*)d_ws;
  float* ctxp = ws;
  float* mw1s = ctxp + 2048 * 512;
  float* b2s  = mw1s + 64 * 512;
  u16*   mw2f = (u16*)(b2s + 512);
  u16*   mw3b = mw2f + 262144;

  prep_w<<<1410, 256, 0, stream>>>(W1, W2, b2, W3, mw1s, mw2f, mw3b, b2s);
  prep_ctx<<<dim3(2048, 2), 256, 0, stream>>>(context, Wc, b1, ctxp);
  made_main<<<512, TPB, 0, stream>>>(eps, b3, ctxp, mw1s, mw3b, b2s, mw2f, out);
}

// Round 10
// 1251.819 us; speedup vs baseline: 1.5999x; 1.0706x over previous
//
#include <hip/hip_runtime.h>
#include <hip/hip_bf16.h>

// D=64, H=512, B=2048, S=16, C=256. Rows = 32768 independent samples, 64 AR steps.
#define ROWS 64      // rows per block
#define TPB 1024     // 16 waves

typedef unsigned short u16;
typedef __attribute__((ext_vector_type(8))) short bf16x8;
typedef __attribute__((ext_vector_type(16))) float f32x16;

__device__ __forceinline__ int deg_of_sorted(int i) {
  return (i < 72) ? (i / 9 + 1) : ((i - 8) / 8 + 1);
}
__device__ __forceinline__ int perm_of_sorted(int i) {
  int g, k;
  if (i < 72) { g = i / 9 + 1; k = i % 9; }
  else        { g = (i - 8) / 8 + 1; k = (i - 8) % 8; }
  return (g - 1) + 63 * k;
}
__device__ __forceinline__ int cum_deg(int d) {
  return (d <= 0) ? 0 : ((d <= 8) ? 9 * d : 8 * d + 8);
}
__device__ __forceinline__ u16 f2bfu(float x) {
  return __builtin_bit_cast(u16, __float2bfloat16(x));
}
__device__ __forceinline__ float bf2f(u16 u) {
  return __builtin_bit_cast(float, ((unsigned)u) << 16);
}
__device__ __forceinline__ float softplus_f(float x) {
  return fmaxf(x, 0.f) + log1pf(expf(-fabsf(x)));
}

// ---------------- prep: permuted/masked weights (unchanged, proven) ----------------
__global__ __launch_bounds__(256) void prep_w(
    const float* __restrict__ W1, const float* __restrict__ W2,
    const float* __restrict__ b2, const float* __restrict__ W3,
    float* __restrict__ mw1s, u16* __restrict__ mw2f,
    u16* __restrict__ mw3b, float* __restrict__ b2s) {
  int idx = blockIdx.x * 256 + threadIdx.x;
  if (idx < 262144) {  // MW2 sorted+masked, MFMA-B fragment layout [(k>>3)][n][k&7]
    int kb = idx >> 12, n = (idx >> 3) & 511, kk = idx & 7;
    int k = kb * 8 + kk;
    float v = (deg_of_sorted(k) <= deg_of_sorted(n))
                  ? W2[perm_of_sorted(k) * 512 + perm_of_sorted(n)] : 0.f;
    mw2f[idx] = f2bfu(v);
    return;
  }
  idx -= 262144;
  if (idx < 32768) {   // MW1 sorted+masked rows d, cols sorted j (f32)
    int d = idx >> 9, j = idx & 511;
    mw1s[idx] = (deg_of_sorted(j) >= d + 1) ? W1[d * 512 + perm_of_sorted(j)] : 0.f;
    return;
  }
  idx -= 32768;
  if (idx < 65536) {   // MW3 transposed bf16: [out col c(128)][sorted j(512)]
    int c = idx >> 9, j = idx & 511;
    float v = (deg_of_sorted(j) <= (c & 63)) ? W3[perm_of_sorted(j) * 128 + c] : 0.f;
    mw3b[idx] = f2bfu(v);
    return;
  }
  idx -= 65536;
  if (idx < 512) b2s[idx] = b2[perm_of_sorted(idx)];
}

__global__ __launch_bounds__(256) void prep_ctx(
    const float* __restrict__ context, const float* __restrict__ Wc,
    const float* __restrict__ b1, float* __restrict__ ctxp) {
  __shared__ float cs[256];
  const int b = blockIdx.x;
  const int j = blockIdx.y * 256 + threadIdx.x;
  cs[threadIdx.x] = context[b * 256 + threadIdx.x];
  __syncthreads();
  const int pj = perm_of_sorted(j);
  float acc = b1[pj];
  #pragma unroll 4
  for (int c = 0; c < 256; ++c) acc += cs[c] * Wc[c * 512 + pj];
  ctxp[b * 512 + j] = acc;
}

// ------- main: pair (p,15-p) split across two waves by row-half; balanced phase A -------
__global__ __launch_bounds__(TPB, 4) void made_main(
    const float* __restrict__ eps, const float* __restrict__ b3,
    const float* __restrict__ ctxp, const float* __restrict__ mw1s,
    const u16* __restrict__ mw3b, const float* __restrict__ b2s,
    const u16* __restrict__ mw2f, float* __restrict__ out) {
  __shared__ __align__(16) u16   h1s[ROWS * 512];   // 65536 B bf16 relu(a1), XOR-swizzled
  __shared__ __align__(16) float part2[128 * 17];   //  8704 B (out,row) x wave partials
  __shared__ __align__(16) float w1s[512];          //  2048 B staged w1 row d
  __shared__ __align__(16) float b3s[128];          //   512 B
  __shared__ __align__(16) float epsall[64 * 65];   // 16640 B all eps for block, stride 65

  const int tid  = threadIdx.x;
  const int lane = tid & 63;
  const int wave = tid >> 6;               // 0..15
  const int g0   = blockIdx.x * ROWS;
  const int b0   = g0 & 2047;

  // a1 ownership: row rA = lane, cols [jA, jA+32)
  const int rA = lane;
  const int jA = wave * 32;
  float a1r[32];
  #pragma unroll
  for (int t = 0; t < 8; ++t) {
    *(float4*)&a1r[t * 4] = *(const float4*)&ctxp[(b0 + rA) * 512 + jA + t * 4];
  }

  // zero h1s; preload b3; stage all eps (coalesced, once)
  #pragma unroll
  for (int i = 0; i < 4; ++i) {
    *(uint4*)&h1s[(tid + i * TPB) * 8] = uint4{0, 0, 0, 0};
  }
  if (tid < 128) b3s[tid] = b3[tid];
  {
    int r = tid >> 4, c = (tid & 15) * 4;
    float4 ev = *(const float4*)&eps[(g0 + r) * 64 + c];
    epsall[r * 65 + c + 0] = ev.x;
    epsall[r * 65 + c + 1] = ev.y;
    epsall[r * 65 + c + 2] = ev.z;
    epsall[r * 65 + c + 3] = ev.w;
  }
  __syncthreads();

  const int m    = lane & 31;   // MFMA A row within half / B col-within-tile
  const int kq   = lane >> 5;   // k-half
  const int p    = (wave < 8) ? wave : 15 - wave;  // pair index (each pair -> 2 waves)
  const int hsel = (wave >= 8);                    // row-half: 0 -> rows 0..31, 1 -> 32..63
  const int hOff = hsel << 5;
  const int jt0  = p;
  const int jt1  = 15 - p;
  const u16* bLane = mw2f + ((kq * 512 + m) << 3);
  const u16* bp0   = bLane + jt0 * 256;
  const u16* bp1   = bLane + jt1 * 256;
  const float b2v0 = b2s[jt0 * 32 + m];
  const float b2v1 = b2s[jt1 * 32 + m];
  const u16* h1m   = h1s + (hOff + m) * 512;   // swizzle key = m (row&31)
  // butterfly output ownership
  const int oi = m & 1;
  const int rowIdx = ((m & 2) << 3) | ((m & 4) << 1) | ((m & 8) >> 2) |
                     ((m & 16) >> 4) | (kq << 2);
  const int ke0full = cum_deg(deg_of_sorted(jt0 * 32 + 31));
  const int ke1full = cum_deg(deg_of_sorted(jt1 * 32 + 31));

  f32x16 acc0, acc1;
  #pragma unroll
  for (int i = 0; i < 16; ++i) { acc0[i] = 0.f; acc1[i] = 0.f; }

  // merged butterfly: pre-sum two tiles' h2*w3 elementwise, then 5-level reduce-scatter
  auto butterfly2 = [&](const f32x16& aT0, const f32x16& aT1,
                        float wmu0, float wmu1, float wsc0, float wsc1) -> float {
    float v[32];
    #pragma unroll
    for (int i = 0; i < 16; ++i) {
      float h20 = fmaxf(aT0[i] + b2v0, 0.f);
      float h21 = fmaxf(aT1[i] + b2v1, 0.f);
      v[i]      = h20 * wmu0 + h21 * wmu1;
      v[16 + i] = h20 * wsc0 + h21 * wsc1;
    }
    const bool s1 = (m & 1);
    #pragma unroll
    for (int j = 0; j < 16; ++j) {
      float snd = s1 ? v[j] : v[j + 16];
      float got = __shfl_xor(snd, 1);
      v[j] = (s1 ? v[j + 16] : v[j]) + got;
    }
    const bool s2 = (m & 2);
    #pragma unroll
    for (int j = 0; j < 8; ++j) {
      float snd = s2 ? v[j] : v[j + 8];
      float got = __shfl_xor(snd, 2);
      v[j] = (s2 ? v[j + 8] : v[j]) + got;
    }
    const bool s4 = (m & 4);
    #pragma unroll
    for (int j = 0; j < 4; ++j) {
      float snd = s4 ? v[j] : v[j + 4];
      float got = __shfl_xor(snd, 4);
      v[j] = (s4 ? v[j + 4] : v[j]) + got;
    }
    const bool s8 = (m & 8);
    #pragma unroll
    for (int j = 0; j < 2; ++j) {
      float snd = s8 ? v[j] : v[j + 2];
      float got = __shfl_xor(snd, 8);
      v[j] = (s8 ? v[j + 2] : v[j]) + got;
    }
    const bool s16 = (m & 16);
    float snd = s16 ? v[0] : v[1];
    float got = __shfl_xor(snd, 16);
    return (s16 ? v[1] : v[0]) + got;
  };

  for (int d = 0; d < 64; ++d) {
    const int Cd    = cum_deg(d);
    const int Cnext = cum_deg(d + 1);
    const int nt    = (Cd + 31) >> 5;
    const int KmaxA = (Cd + 15) & ~15;

    // --- stage-issue (consumed after phase A)
    const float wmu0 = bf2f(mw3b[d * 512 + jt0 * 32 + m]);
    const float wmu1 = bf2f(mw3b[d * 512 + jt1 * 32 + m]);
    const float wsc0 = bf2f(mw3b[(64 + d) * 512 + jt0 * 32 + m]);
    const float wsc1 = bf2f(mw3b[(64 + d) * 512 + jt1 * 32 + m]);
    float4 w1stg;
    if (tid < 128) w1stg = *(const float4*)&mw1s[d * 512 + tid * 4];

    // --- Phase A: one row-half of the balanced tile pair
    {
      int ke0 = (jt0 < nt) ? (ke0full > KmaxA ? KmaxA : ke0full) : 0;
      int ke1 = (jt1 < nt) ? (ke1full > KmaxA ? KmaxA : ke1full) : 0;
      const int n0 = (ke0 + 15) >> 4;
      const int n1 = (ke1 + 15) >> 4;
      const int ns = n0 < n1 ? n0 : n1;
      #pragma unroll
      for (int i = 0; i < 16; ++i) { acc0[i] = 0.f; acc1[i] = 0.f; }
      for (int ks = 0; ks < ns; ++ks) {
        const int off = (((2 * ks + kq)) ^ m) << 3;
        bf16x8 aF = *(const bf16x8*)(h1m + off);
        bf16x8 bA = *(const bf16x8*)(bp0 + ks * 8192);
        bf16x8 bB = *(const bf16x8*)(bp1 + ks * 8192);
        acc0 = __builtin_amdgcn_mfma_f32_32x32x16_bf16(aF, bA, acc0, 0, 0, 0);
        acc1 = __builtin_amdgcn_mfma_f32_32x32x16_bf16(aF, bB, acc1, 0, 0, 0);
      }
      if (n0 > ns) {
        for (int ks = ns; ks < n0; ++ks) {
          const int off = (((2 * ks + kq)) ^ m) << 3;
          bf16x8 aF = *(const bf16x8*)(h1m + off);
          bf16x8 bA = *(const bf16x8*)(bp0 + ks * 8192);
          acc0 = __builtin_amdgcn_mfma_f32_32x32x16_bf16(aF, bA, acc0, 0, 0, 0);
        }
      } else if (n1 > ns) {
        for (int ks = ns; ks < n1; ++ks) {
          const int off = (((2 * ks + kq)) ^ m) << 3;
          bf16x8 aF = *(const bf16x8*)(h1m + off);
          bf16x8 bB = *(const bf16x8*)(bp1 + ks * 8192);
          acc1 = __builtin_amdgcn_mfma_f32_32x32x16_bf16(aF, bB, acc1, 0, 0, 0);
        }
      }
    }

    // --- Phase B: merged butterfly -> one partial per lane for this row-half
    float p0 = butterfly2(acc0, acc1, wmu0, wmu1, wsc0, wsc1);
    part2[(oi * 64 + hOff + rowIdx) * 17 + wave] = p0;

    // --- stage-write (latency hidden under phase A/B)
    if (tid < 128) *(float4*)&w1s[tid * 4] = w1stg;
    __syncthreads();

    // --- B2 (replicated): sum the 8 waves that own this row-half, softplus, sample
    const int wb = (rA >= 32) ? 8 : 0;
    float msum = b3s[d], ssum = b3s[64 + d];
    #pragma unroll
    for (int w = 0; w < 8; ++w) {
      msum += part2[rA * 17 + wb + w];
      ssum += part2[(64 + rA) * 17 + wb + w];
    }
    const float mu = msum;
    const float sc = softplus_f(ssum);
    const float z  = fmaf(sc, epsall[rA * 65 + d], mu);
    if (tid < 64) {
      out[(g0 + rA) * 64 + d]           = z;
      out[2097152 + (g0 + rA) * 64 + d] = mu;
      out[4194304 + (g0 + rA) * 64 + d] = sc;
    }

    // --- Phase C: rank-1 a1 update on owned slice + incremental h1 freeze
    if (jA + 31 >= Cd) {
      #pragma unroll
      for (int i = 0; i < 32; ++i) {
        int j = jA + i;
        if (j >= Cd) a1r[i] += z * w1s[j];
      }
      if (jA < Cnext) {
        #pragma unroll
        for (int i = 0; i < 32; ++i) {
          int j = jA + i;
          if (j >= Cd && j < Cnext) {
            h1s[rA * 512 + (((((j >> 3) ^ (rA & 31))) << 3) | (j & 7))] =
                f2bfu(fmaxf(a1r[i], 0.f));
          }
        }
      }
    }
    __syncthreads();
  }
}

extern "C" void kernel_launch(void* const* d_in, const int* in_sizes, int n_in,
                              void* d_out, int out_size, void* d_ws, size_t ws_size,
                              hipStream_t stream) {
  (void)in_sizes; (void)n_in; (void)out_size; (void)ws_size;
  const float* context = (const float*)d_in[0];
  const float* eps     = (const float*)d_in[1];
  const float* W1      = (const float*)d_in[2];
  const float* Wc      = (const float*)d_in[3];
  const float* b1      = (const float*)d_in[4];
  const float* W2      = (const float*)d_in[5];
  const float* b2      = (const float*)d_in[6];
  const float* W3      = (const float*)d_in[7];
  const float* b3      = (const float*)d_in[8];
  float* out = (float*)d_out;

  // ws: ctxp f32[2048*512] | mw1s f32[64*512] | b2s f32[512] | mw2f u16[262144] | mw3b u16[65536]
  float* ws   = (float*)d_ws;
  float* ctxp = ws;
  float* mw1s = ctxp + 2048 * 512;
  float* b2s  = mw1s + 64 * 512;
  u16*   mw2f = (u16*)(b2s + 512);
  u16*   mw3b = mw2f + 262144;

  prep_w<<<1410, 256, 0, stream>>>(W1, W2, b2, W3, mw1s, mw2f, mw3b, b2s);
  prep_ctx<<<dim3(2048, 2), 256, 0, stream>>>(context, Wc, b1, ctxp);
  made_main<<<512, TPB, 0, stream>>>(eps, b3, ctxp, mw1s, mw3b, b2s, mw2f, out);
}

// Round 11
// 1095.796 us; speedup vs baseline: 1.8277x; 1.1424x over previous
//
#include <hip/hip_runtime.h>
#include <hip/hip_bf16.h>

// D=64, H=512, B=2048, S=16, C=256. Rows = 32768 independent samples, 64 AR steps.
#define ROWS 32      // rows per block
#define TPB 512      // 8 waves; target 2 blocks/CU

typedef unsigned short u16;
typedef __attribute__((ext_vector_type(8))) short bf16x8;
typedef __attribute__((ext_vector_type(16))) float f32x16;

__device__ __forceinline__ int deg_of_sorted(int i) {
  return (i < 72) ? (i / 9 + 1) : ((i - 8) / 8 + 1);
}
__device__ __forceinline__ int perm_of_sorted(int i) {
  int g, k;
  if (i < 72) { g = i / 9 + 1; k = i % 9; }
  else        { g = (i - 8) / 8 + 1; k = (i - 8) % 8; }
  return (g - 1) + 63 * k;
}
__device__ __forceinline__ int cum_deg(int d) {
  return (d <= 0) ? 0 : ((d <= 8) ? 9 * d : 8 * d + 8);
}
__device__ __forceinline__ u16 f2bfu(float x) {
  return __builtin_bit_cast(u16, __float2bfloat16(x));
}
__device__ __forceinline__ float bf2f(u16 u) {
  return __builtin_bit_cast(float, ((unsigned)u) << 16);
}
__device__ __forceinline__ float softplus_f(float x) {
  return fmaxf(x, 0.f) + log1pf(expf(-fabsf(x)));
}

// ---------------- prep: permuted/masked weights (unchanged, proven) ----------------
__global__ __launch_bounds__(256) void prep_w(
    const float* __restrict__ W1, const float* __restrict__ W2,
    const float* __restrict__ b2, const float* __restrict__ W3,
    float* __restrict__ mw1s, u16* __restrict__ mw2f,
    u16* __restrict__ mw3b, float* __restrict__ b2s) {
  int idx = blockIdx.x * 256 + threadIdx.x;
  if (idx < 262144) {  // MW2 sorted+masked, MFMA-B fragment layout [(k>>3)][n][k&7]
    int kb = idx >> 12, n = (idx >> 3) & 511, kk = idx & 7;
    int k = kb * 8 + kk;
    float v = (deg_of_sorted(k) <= deg_of_sorted(n))
                  ? W2[perm_of_sorted(k) * 512 + perm_of_sorted(n)] : 0.f;
    mw2f[idx] = f2bfu(v);
    return;
  }
  idx -= 262144;
  if (idx < 32768) {   // MW1 sorted+masked rows d, cols sorted j (f32)
    int d = idx >> 9, j = idx & 511;
    mw1s[idx] = (deg_of_sorted(j) >= d + 1) ? W1[d * 512 + perm_of_sorted(j)] : 0.f;
    return;
  }
  idx -= 32768;
  if (idx < 65536) {   // MW3 transposed bf16: [out col c(128)][sorted j(512)]
    int c = idx >> 9, j = idx & 511;
    float v = (deg_of_sorted(j) <= (c & 63)) ? W3[perm_of_sorted(j) * 128 + c] : 0.f;
    mw3b[idx] = f2bfu(v);
    return;
  }
  idx -= 65536;
  if (idx < 512) b2s[idx] = b2[perm_of_sorted(idx)];
}

__global__ __launch_bounds__(256) void prep_ctx(
    const float* __restrict__ context, const float* __restrict__ Wc,
    const float* __restrict__ b1, float* __restrict__ ctxp) {
  __shared__ float cs[256];
  const int b = blockIdx.x;
  const int j = blockIdx.y * 256 + threadIdx.x;
  cs[threadIdx.x] = context[b * 256 + threadIdx.x];
  __syncthreads();
  const int pj = perm_of_sorted(j);
  float acc = b1[pj];
  #pragma unroll 4
  for (int c = 0; c < 256; ++c) acc += cs[c] * Wc[c * 512 + pj];
  ctxp[b * 512 + j] = acc;
}

// ------- main: 32 rows/block, 8 waves (pair per wave), 2 blocks/CU, LDS-buffered out ----
__global__ __launch_bounds__(TPB, 4) void made_main(
    const float* __restrict__ eps, const float* __restrict__ b3,
    const float* __restrict__ ctxp, const float* __restrict__ mw1s,
    const u16* __restrict__ mw3b, const float* __restrict__ b2s,
    const u16* __restrict__ mw2f, float* __restrict__ out) {
  __shared__ __align__(16) u16   h1s[ROWS * 512];   // 32768 B bf16 relu(a1), XOR-swizzled
  __shared__ __align__(16) float part2[64 * 9];     //  2304 B (out,row) x wave partials
  __shared__ __align__(16) float w1s[512];          //  2048 B staged w1 row d
  __shared__ __align__(16) float b3s[128];          //   512 B
  __shared__ __align__(16) float epsall[ROWS * 65]; //  8320 B eps rows, stride 65
  __shared__ __align__(16) float zLb[ROWS * 65];    //  8320 B z buffer
  __shared__ __align__(16) float muLb[ROWS * 65];   //  8320 B mu buffer
  __shared__ __align__(16) float scLb[ROWS * 65];   //  8320 B scale buffer
  // total ~70.9 KB -> 2 blocks/CU

  const int tid  = threadIdx.x;
  const int lane = tid & 63;
  const int wave = tid >> 6;               // 0..7
  const int g0   = blockIdx.x * ROWS;
  const int b0   = g0 & 2047;

  // a1 ownership: row rA = tid&31, cols [jA, jA+32)
  const int rA = tid & 31;
  const int jA = (tid >> 5) << 5;          // 16 col-groups of 32
  float a1r[32];
  #pragma unroll
  for (int t = 0; t < 8; ++t) {
    *(float4*)&a1r[t * 4] = *(const float4*)&ctxp[(b0 + rA) * 512 + jA + t * 4];
  }

  // zero h1s; preload b3; stage all eps (coalesced, once)
  #pragma unroll
  for (int i = 0; i < 4; ++i) {
    *(uint4*)&h1s[(tid + i * TPB) * 8] = uint4{0, 0, 0, 0};
  }
  if (tid < 128) b3s[tid] = b3[tid];
  {
    int r = tid >> 4, c = (tid & 15) * 4;
    float4 ev = *(const float4*)&eps[(g0 + r) * 64 + c];
    epsall[r * 65 + c + 0] = ev.x;
    epsall[r * 65 + c + 1] = ev.y;
    epsall[r * 65 + c + 2] = ev.z;
    epsall[r * 65 + c + 3] = ev.w;
  }
  __syncthreads();

  const int m  = lane & 31;   // MFMA A row / B col-within-tile
  const int kq = lane >> 5;   // k-half
  const int jt0 = wave;       // balanced pair per wave
  const int jt1 = 15 - wave;
  const u16* bLane = mw2f + ((kq * 512 + m) << 3);
  const u16* bp0   = bLane + jt0 * 256;
  const u16* bp1   = bLane + jt1 * 256;
  const float b2v0 = b2s[jt0 * 32 + m];
  const float b2v1 = b2s[jt1 * 32 + m];
  const u16* h1m   = h1s + m * 512;        // swizzle key = m
  const int oi = m & 1;
  const int rowIdx = ((m & 2) << 3) | ((m & 4) << 1) | ((m & 8) >> 2) |
                     ((m & 16) >> 4) | (kq << 2);
  const int ke0full = cum_deg(deg_of_sorted(jt0 * 32 + 31));
  const int ke1full = cum_deg(deg_of_sorted(jt1 * 32 + 31));

  f32x16 acc0, acc1;
  #pragma unroll
  for (int i = 0; i < 16; ++i) { acc0[i] = 0.f; acc1[i] = 0.f; }

  auto butterfly2 = [&](const f32x16& aT0, const f32x16& aT1,
                        float wmu0, float wmu1, float wsc0, float wsc1) -> float {
    float v[32];
    #pragma unroll
    for (int i = 0; i < 16; ++i) {
      float h20 = fmaxf(aT0[i] + b2v0, 0.f);
      float h21 = fmaxf(aT1[i] + b2v1, 0.f);
      v[i]      = h20 * wmu0 + h21 * wmu1;
      v[16 + i] = h20 * wsc0 + h21 * wsc1;
    }
    const bool s1 = (m & 1);
    #pragma unroll
    for (int j = 0; j < 16; ++j) {
      float snd = s1 ? v[j] : v[j + 16];
      float got = __shfl_xor(snd, 1);
      v[j] = (s1 ? v[j + 16] : v[j]) + got;
    }
    const bool s2 = (m & 2);
    #pragma unroll
    for (int j = 0; j < 8; ++j) {
      float snd = s2 ? v[j] : v[j + 8];
      float got = __shfl_xor(snd, 2);
      v[j] = (s2 ? v[j + 8] : v[j]) + got;
    }
    const bool s4 = (m & 4);
    #pragma unroll
    for (int j = 0; j < 4; ++j) {
      float snd = s4 ? v[j] : v[j + 4];
      float got = __shfl_xor(snd, 4);
      v[j] = (s4 ? v[j + 4] : v[j]) + got;
    }
    const bool s8 = (m & 8);
    #pragma unroll
    for (int j = 0; j < 2; ++j) {
      float snd = s8 ? v[j] : v[j + 2];
      float got = __shfl_xor(snd, 8);
      v[j] = (s8 ? v[j + 2] : v[j]) + got;
    }
    const bool s16 = (m & 16);
    float snd = s16 ? v[0] : v[1];
    float got = __shfl_xor(snd, 16);
    return (s16 ? v[1] : v[0]) + got;
  };

  for (int d = 0; d < 64; ++d) {
    const int Cd    = cum_deg(d);
    const int Cnext = cum_deg(d + 1);
    const int nt    = (Cd + 31) >> 5;
    const int KmaxA = (Cd + 15) & ~15;

    // --- stage-issue (consumed after phase A)
    const float wmu0 = bf2f(mw3b[d * 512 + jt0 * 32 + m]);
    const float wmu1 = bf2f(mw3b[d * 512 + jt1 * 32 + m]);
    const float wsc0 = bf2f(mw3b[(64 + d) * 512 + jt0 * 32 + m]);
    const float wsc1 = bf2f(mw3b[(64 + d) * 512 + jt1 * 32 + m]);
    float4 w1stg;
    if (tid < 128) w1stg = *(const float4*)&mw1s[d * 512 + tid * 4];

    // --- Phase A: balanced pair (both tiles, M=32), 2x unrolled for load pipelining
    {
      int ke0 = (jt0 < nt) ? (ke0full > KmaxA ? KmaxA : ke0full) : 0;
      int ke1 = (jt1 < nt) ? (ke1full > KmaxA ? KmaxA : ke1full) : 0;
      const int n0 = (ke0 + 15) >> 4;
      const int n1 = (ke1 + 15) >> 4;
      const int ns = n0 < n1 ? n0 : n1;
      #pragma unroll
      for (int i = 0; i < 16; ++i) { acc0[i] = 0.f; acc1[i] = 0.f; }
      int ks = 0;
      for (; ks + 2 <= ns; ks += 2) {
        bf16x8 bA0 = *(const bf16x8*)(bp0 + (ks + 0) * 8192);
        bf16x8 bB0 = *(const bf16x8*)(bp1 + (ks + 0) * 8192);
        bf16x8 bA1 = *(const bf16x8*)(bp0 + (ks + 1) * 8192);
        bf16x8 bB1 = *(const bf16x8*)(bp1 + (ks + 1) * 8192);
        bf16x8 aF0 = *(const bf16x8*)(h1m + (((2 * ks + 0 + kq) ^ m) << 3));
        bf16x8 aF1 = *(const bf16x8*)(h1m + (((2 * ks + 2 + kq) ^ m) << 3));
        acc0 = __builtin_amdgcn_mfma_f32_32x32x16_bf16(aF0, bA0, acc0, 0, 0, 0);
        acc1 = __builtin_amdgcn_mfma_f32_32x32x16_bf16(aF0, bB0, acc1, 0, 0, 0);
        acc0 = __builtin_amdgcn_mfma_f32_32x32x16_bf16(aF1, bA1, acc0, 0, 0, 0);
        acc1 = __builtin_amdgcn_mfma_f32_32x32x16_bf16(aF1, bB1, acc1, 0, 0, 0);
      }
      for (; ks < ns; ++ks) {
        bf16x8 aF = *(const bf16x8*)(h1m + (((2 * ks + kq) ^ m) << 3));
        bf16x8 bA = *(const bf16x8*)(bp0 + ks * 8192);
        bf16x8 bB = *(const bf16x8*)(bp1 + ks * 8192);
        acc0 = __builtin_amdgcn_mfma_f32_32x32x16_bf16(aF, bA, acc0, 0, 0, 0);
        acc1 = __builtin_amdgcn_mfma_f32_32x32x16_bf16(aF, bB, acc1, 0, 0, 0);
      }
      if (n0 > ns) {
        for (; ks < n0; ++ks) {
          bf16x8 aF = *(const bf16x8*)(h1m + (((2 * ks + kq) ^ m) << 3));
          bf16x8 bA = *(const bf16x8*)(bp0 + ks * 8192);
          acc0 = __builtin_amdgcn_mfma_f32_32x32x16_bf16(aF, bA, acc0, 0, 0, 0);
        }
      } else if (n1 > ns) {
        for (; ks < n1; ++ks) {
          bf16x8 aF = *(const bf16x8*)(h1m + (((2 * ks + kq) ^ m) << 3));
          bf16x8 bB = *(const bf16x8*)(bp1 + ks * 8192);
          acc1 = __builtin_amdgcn_mfma_f32_32x32x16_bf16(aF, bB, acc1, 0, 0, 0);
        }
      }
    }

    // --- Phase B: merged butterfly -> one partial per lane
    float pv = butterfly2(acc0, acc1, wmu0, wmu1, wsc0, wsc1);
    part2[(oi * 32 + rowIdx) * 9 + wave] = pv;

    // --- stage-write (latency hidden under phase A/B)
    if (tid < 128) *(float4*)&w1s[tid * 4] = w1stg;
    __syncthreads();

    // --- B2 (replicated all threads): sum 8 wave partials, softplus, sample
    float msum = b3s[d], ssum = b3s[64 + d];
    #pragma unroll
    for (int w = 0; w < 8; ++w) {
      msum += part2[rA * 9 + w];
      ssum += part2[(32 + rA) * 9 + w];
    }
    const float mu = msum;
    const float sc = softplus_f(ssum);
    const float z  = fmaf(sc, epsall[rA * 65 + d], mu);
    if (tid < 32) {            // one writer per row; conflict-free (stride 65)
      zLb[rA * 65 + d]  = z;
      muLb[rA * 65 + d] = mu;
      scLb[rA * 65 + d] = sc;
    }

    // --- Phase C: rank-1 a1 update on owned slice + incremental h1 freeze
    if (jA + 31 >= Cd) {
      #pragma unroll
      for (int i = 0; i < 32; ++i) {
        int j = jA + i;
        if (j >= Cd) a1r[i] += z * w1s[j];
      }
      if (jA < Cnext) {
        #pragma unroll
        for (int i = 0; i < 32; ++i) {
          int j = jA + i;
          if (j >= Cd && j < Cnext) {
            h1s[rA * 512 + (((((j >> 3) ^ rA)) << 3) | (j & 7))] =
                f2bfu(fmaxf(a1r[i], 0.f));
          }
        }
      }
    }
    __syncthreads();
  }

  // --- final coalesced flush of z/mu/sc (one float4 per array per thread)
  {
    const int r = tid >> 4, c = (tid & 15) * 4;
    float4 zv, mv, sv;
    zv.x = zLb[r * 65 + c + 0]; zv.y = zLb[r * 65 + c + 1];
    zv.z = zLb[r * 65 + c + 2]; zv.w = zLb[r * 65 + c + 3];
    mv.x = muLb[r * 65 + c + 0]; mv.y = muLb[r * 65 + c + 1];
    mv.z = muLb[r * 65 + c + 2]; mv.w = muLb[r * 65 + c + 3];
    sv.x = scLb[r * 65 + c + 0]; sv.y = scLb[r * 65 + c + 1];
    sv.z = scLb[r * 65 + c + 2]; sv.w = scLb[r * 65 + c + 3];
    *(float4*)&out[(g0 + r) * 64 + c]           = zv;
    *(float4*)&out[2097152 + (g0 + r) * 64 + c] = mv;
    *(float4*)&out[4194304 + (g0 + r) * 64 + c] = sv;
  }
}

extern "C" void kernel_launch(void* const* d_in, const int* in_sizes, int n_in,
                              void* d_out, int out_size, void* d_ws, size_t ws_size,
                              hipStream_t stream) {
  (void)in_sizes; (void)n_in; (void)out_size; (void)ws_size;
  const float* context = (const float*)d_in[0];
  const float* eps     = (const float*)d_in[1];
  const float* W1      = (const float*)d_in[2];
  const float* Wc      = (const float*)d_in[3];
  const float* b1      = (const float*)d_in[4];
  const float* W2      = (const float*)d_in[5];
  const float* b2      = (const float*)d_in[6];
  const float* W3      = (const float*)d_in[7];
  const float* b3      = (const float*)d_in[8];
  float* out = (float*)d_out;

  // ws: ctxp f32[2048*512] | mw1s f32[64*512] | b2s f32[512] | mw2f u16[262144] | mw3b u16[65536]
  float* ws   = (float*)d_ws;
  float* ctxp = ws;
  float* mw1s = ctxp + 2048 * 512;
  float* b2s  = mw1s + 64 * 512;
  u16*   mw2f = (u16*)(b2s + 512);
  u16*   mw3b = mw2f + 262144;

  prep_w<<<1410, 256, 0, stream>>>(W1, W2, b2, W3, mw1s, mw2f, mw3b, b2s);
  prep_ctx<<<dim3(2048, 2), 256, 0, stream>>>(context, Wc, b1, ctxp);
  made_main<<<1024, TPB, 0, stream>>>(eps, b3, ctxp, mw1s, mw3b, b2s, mw2f, out);
}

// Round 12
// 829.215 us; speedup vs baseline: 2.4153x; 1.3215x over previous
//
#include <hip/hip_runtime.h>
#include <hip/hip_bf16.h>

// D=64, H=512, B=2048, S=16, C=256. Rows = 32768 independent samples, 64 AR steps.
#define ROWS 32      // rows per block
#define TPB 512      // 8 waves; 2 blocks/CU

typedef unsigned short u16;
typedef __attribute__((ext_vector_type(8))) short bf16x8;
typedef __attribute__((ext_vector_type(16))) float f32x16;

__device__ __forceinline__ int deg_of_sorted(int i) {
  return (i < 72) ? (i / 9 + 1) : ((i - 8) / 8 + 1);
}
__device__ __forceinline__ int perm_of_sorted(int i) {
  int g, k;
  if (i < 72) { g = i / 9 + 1; k = i % 9; }
  else        { g = (i - 8) / 8 + 1; k = (i - 8) % 8; }
  return (g - 1) + 63 * k;
}
__device__ __forceinline__ int cum_deg(int d) {
  return (d <= 0) ? 0 : ((d <= 8) ? 9 * d : 8 * d + 8);
}
__device__ __forceinline__ u16 f2bfu(float x) {
  return __builtin_bit_cast(u16, __float2bfloat16(x));
}
__device__ __forceinline__ float bf2f(u16 u) {
  return __builtin_bit_cast(float, ((unsigned)u) << 16);
}
__device__ __forceinline__ float softplus_f(float x) {
  return fmaxf(x, 0.f) + log1pf(expf(-fabsf(x)));
}

// ---------------- prep: permuted/masked weights (unchanged, proven) ----------------
__global__ __launch_bounds__(256) void prep_w(
    const float* __restrict__ W1, const float* __restrict__ W2,
    const float* __restrict__ b2, const float* __restrict__ W3,
    float* __restrict__ mw1s, u16* __restrict__ mw2f,
    u16* __restrict__ mw3b, float* __restrict__ b2s) {
  int idx = blockIdx.x * 256 + threadIdx.x;
  if (idx < 262144) {  // MW2 sorted+masked, MFMA-B fragment layout [(k>>3)][n][k&7]
    int kb = idx >> 12, n = (idx >> 3) & 511, kk = idx & 7;
    int k = kb * 8 + kk;
    float v = (deg_of_sorted(k) <= deg_of_sorted(n))
                  ? W2[perm_of_sorted(k) * 512 + perm_of_sorted(n)] : 0.f;
    mw2f[idx] = f2bfu(v);
    return;
  }
  idx -= 262144;
  if (idx < 32768) {   // MW1 sorted+masked rows d, cols sorted j (f32)
    int d = idx >> 9, j = idx & 511;
    mw1s[idx] = (deg_of_sorted(j) >= d + 1) ? W1[d * 512 + perm_of_sorted(j)] : 0.f;
    return;
  }
  idx -= 32768;
  if (idx < 65536) {   // MW3 transposed bf16: [out col c(128)][sorted j(512)]
    int c = idx >> 9, j = idx & 511;
    float v = (deg_of_sorted(j) <= (c & 63)) ? W3[perm_of_sorted(j) * 128 + c] : 0.f;
    mw3b[idx] = f2bfu(v);
    return;
  }
  idx -= 65536;
  if (idx < 512) b2s[idx] = b2[perm_of_sorted(idx)];
}

__global__ __launch_bounds__(256) void prep_ctx(
    const float* __restrict__ context, const float* __restrict__ Wc,
    const float* __restrict__ b1, float* __restrict__ ctxp) {
  __shared__ float cs[256];
  const int b = blockIdx.x;
  const int j = blockIdx.y * 256 + threadIdx.x;
  cs[threadIdx.x] = context[b * 256 + threadIdx.x];
  __syncthreads();
  const int pj = perm_of_sorted(j);
  float acc = b1[pj];
  #pragma unroll 4
  for (int c = 0; c < 256; ++c) acc += cs[c] * Wc[c * 512 + pj];
  ctxp[b * 512 + j] = acc;
}

// ---- main: persistent layer-2 accumulator; per-step delta MFMA over new frozen cols ----
__global__ __launch_bounds__(TPB, 4) void made_main(
    const float* __restrict__ eps, const float* __restrict__ b3,
    const float* __restrict__ ctxp, const float* __restrict__ mw1s,
    const u16* __restrict__ mw3b, const float* __restrict__ b2s,
    const u16* __restrict__ mw2f, float* __restrict__ out) {
  __shared__ __align__(16) u16   dbuf[2][32][32];   //  4096 B delta h1 (double-buffered)
  __shared__ __align__(16) float part2[64 * 9];     //  2304 B (out,row) x wave partials
  __shared__ __align__(16) float w1s[512];          //  2048 B staged w1 row d
  __shared__ __align__(16) float b3s[128];          //   512 B
  __shared__ __align__(16) float epsall[ROWS * 65]; //  8320 B eps rows, stride 65
  __shared__ __align__(16) float zLb[ROWS * 65];    //  8320 B z buffer
  __shared__ __align__(16) float muLb[ROWS * 65];   //  8320 B mu buffer
  __shared__ __align__(16) float scLb[ROWS * 65];   //  8320 B scale buffer
  // total ~42 KB

  const int tid  = threadIdx.x;
  const int lane = tid & 63;
  const int wave = tid >> 6;               // 0..7
  const int g0   = blockIdx.x * ROWS;
  const int b0   = g0 & 2047;

  // a1 ownership: row rA = tid&31, cols [jA, jA+32)
  const int rA = tid & 31;
  const int jA = (tid >> 5) << 5;          // 16 col-groups of 32
  float a1r[32];
  #pragma unroll
  for (int t = 0; t < 8; ++t) {
    *(float4*)&a1r[t * 4] = *(const float4*)&ctxp[(b0 + rA) * 512 + jA + t * 4];
  }

  // zero both delta buffers; preload b3; stage all eps (coalesced, once)
  ((unsigned*)dbuf)[tid] = 0u;
  ((unsigned*)dbuf)[tid + 512] = 0u;
  if (tid < 128) b3s[tid] = b3[tid];
  {
    int r = tid >> 4, c = (tid & 15) * 4;
    float4 ev = *(const float4*)&eps[(g0 + r) * 64 + c];
    epsall[r * 65 + c + 0] = ev.x;
    epsall[r * 65 + c + 1] = ev.y;
    epsall[r * 65 + c + 2] = ev.z;
    epsall[r * 65 + c + 3] = ev.w;
  }
  __syncthreads();

  const int m  = lane & 31;   // MFMA A row / B col-within-tile
  const int kq = lane >> 5;   // k-half
  const int jt0 = wave;       // balanced pair per wave
  const int jt1 = 15 - wave;
  const u16* bLane = mw2f + ((kq * 512 + m) << 3);
  const u16* bp0   = bLane + jt0 * 256;
  const u16* bp1   = bLane + jt1 * 256;
  const float b2v0 = b2s[jt0 * 32 + m];
  const float b2v1 = b2s[jt1 * 32 + m];
  const int oi = m & 1;
  const int rowIdx = ((m & 2) << 3) | ((m & 4) << 1) | ((m & 8) >> 2) |
                     ((m & 16) >> 4) | (kq << 2);
  const int ke0full = cum_deg(deg_of_sorted(jt0 * 32 + 31));
  const int ke1full = cum_deg(deg_of_sorted(jt1 * 32 + 31));

  // persistent layer-2 pre-activation accumulators (exact: masked weights are 0)
  f32x16 acc0, acc1;
  #pragma unroll
  for (int i = 0; i < 16; ++i) { acc0[i] = 0.f; acc1[i] = 0.f; }

  auto butterfly2 = [&](const f32x16& aT0, const f32x16& aT1,
                        float wmu0, float wmu1, float wsc0, float wsc1) -> float {
    float v[32];
    #pragma unroll
    for (int i = 0; i < 16; ++i) {
      float h20 = fmaxf(aT0[i] + b2v0, 0.f);
      float h21 = fmaxf(aT1[i] + b2v1, 0.f);
      v[i]      = h20 * wmu0 + h21 * wmu1;
      v[16 + i] = h20 * wsc0 + h21 * wsc1;
    }
    const bool s1 = (m & 1);
    #pragma unroll
    for (int j = 0; j < 16; ++j) {
      float snd = s1 ? v[j] : v[j + 16];
      float got = __shfl_xor(snd, 1);
      v[j] = (s1 ? v[j + 16] : v[j]) + got;
    }
    const bool s2 = (m & 2);
    #pragma unroll
    for (int j = 0; j < 8; ++j) {
      float snd = s2 ? v[j] : v[j + 8];
      float got = __shfl_xor(snd, 2);
      v[j] = (s2 ? v[j + 8] : v[j]) + got;
    }
    const bool s4 = (m & 4);
    #pragma unroll
    for (int j = 0; j < 4; ++j) {
      float snd = s4 ? v[j] : v[j + 4];
      float got = __shfl_xor(snd, 4);
      v[j] = (s4 ? v[j + 4] : v[j]) + got;
    }
    const bool s8 = (m & 8);
    #pragma unroll
    for (int j = 0; j < 2; ++j) {
      float snd = s8 ? v[j] : v[j + 2];
      float got = __shfl_xor(snd, 8);
      v[j] = (s8 ? v[j + 2] : v[j]) + got;
    }
    const bool s16 = (m & 16);
    float snd = s16 ? v[0] : v[1];
    float got = __shfl_xor(snd, 16);
    return (s16 ? v[1] : v[0]) + got;
  };

  for (int d = 0; d < 64; ++d) {
    const int Cd    = cum_deg(d);
    const int Cnext = cum_deg(d + 1);
    const int Cprev = cum_deg(d - 1);       // d=0 -> 0
    const int cb    = d & 1;                // delta buffer read this step
    const int nb    = cb ^ 1;               // delta buffer written for next step

    // --- stage-issue (consumed after phase A/B)
    const float wmu0 = bf2f(mw3b[d * 512 + jt0 * 32 + m]);
    const float wmu1 = bf2f(mw3b[d * 512 + jt1 * 32 + m]);
    const float wsc0 = bf2f(mw3b[(64 + d) * 512 + jt0 * 32 + m]);
    const float wsc1 = bf2f(mw3b[(64 + d) * 512 + jt1 * 32 + m]);
    float4 w1stg;
    if (tid < 128) w1stg = *(const float4*)&mw1s[d * 512 + tid * 4];

    // --- Phase A: delta MFMA — add newly frozen cols [Cprev, Cd) to persistent acc
    if (d > 0) {
      const int kb  = Cprev >> 4;                  // delta window base kstep
      const int nks = ((Cd - 1) >> 4) - kb + 1;    // 1 or 2
      #pragma unroll 2
      for (int t = 0; t < nks; ++t) {
        const int ks = kb + t;
        bf16x8 aF = *(const bf16x8*)((const u16*)&dbuf[cb][m][0] + t * 16 + kq * 8);
        if (ke0full > ks * 16) {
          bf16x8 bA = *(const bf16x8*)(bp0 + ks * 8192);
          acc0 = __builtin_amdgcn_mfma_f32_32x32x16_bf16(aF, bA, acc0, 0, 0, 0);
        }
        if (ke1full > ks * 16) {
          bf16x8 bB = *(const bf16x8*)(bp1 + ks * 8192);
          acc1 = __builtin_amdgcn_mfma_f32_32x32x16_bf16(aF, bB, acc1, 0, 0, 0);
        }
      }
    }

    // --- Phase B: merged butterfly -> one partial per lane
    float pv = butterfly2(acc0, acc1, wmu0, wmu1, wsc0, wsc1);
    part2[(oi * 32 + rowIdx) * 9 + wave] = pv;

    // zero next delta buffer (last read of it was >=1 barrier ago)
    ((unsigned*)dbuf[nb])[tid] = 0u;

    // stage-write (latency hidden under phase A/B)
    if (tid < 128) *(float4*)&w1s[tid * 4] = w1stg;
    __syncthreads();

    // --- B2 (replicated all threads): sum 8 wave partials, softplus, sample
    float msum = b3s[d], ssum = b3s[64 + d];
    #pragma unroll
    for (int w = 0; w < 8; ++w) {
      msum += part2[rA * 9 + w];
      ssum += part2[(32 + rA) * 9 + w];
    }
    const float mu = msum;
    const float sc = softplus_f(ssum);
    const float z  = fmaf(sc, epsall[rA * 65 + d], mu);
    if (tid < 32) {            // one writer per row; conflict-free (stride 65)
      zLb[rA * 65 + d]  = z;
      muLb[rA * 65 + d] = mu;
      scLb[rA * 65 + d] = sc;
    }

    // --- Phase C: rank-1 a1 update on owned slice + freeze new cols into next delta
    if (jA + 31 >= Cd) {
      const int kbw = Cd >> 4;               // next step's delta window base
      #pragma unroll
      for (int i = 0; i < 32; ++i) {
        int j = jA + i;
        if (j >= Cd) a1r[i] += z * w1s[j];
      }
      if (jA < Cnext) {
        #pragma unroll
        for (int i = 0; i < 32; ++i) {
          int j = jA + i;
          if (j >= Cd && j < Cnext) {
            dbuf[nb][rA][j - kbw * 16] = f2bfu(fmaxf(a1r[i], 0.f));
          }
        }
      }
    }
    __syncthreads();
  }

  // --- final coalesced flush of z/mu/sc (one float4 per array per thread)
  {
    const int r = tid >> 4, c = (tid & 15) * 4;
    float4 zv, mv, sv;
    zv.x = zLb[r * 65 + c + 0]; zv.y = zLb[r * 65 + c + 1];
    zv.z = zLb[r * 65 + c + 2]; zv.w = zLb[r * 65 + c + 3];
    mv.x = muLb[r * 65 + c + 0]; mv.y = muLb[r * 65 + c + 1];
    mv.z = muLb[r * 65 + c + 2]; mv.w = muLb[r * 65 + c + 3];
    sv.x = scLb[r * 65 + c + 0]; sv.y = scLb[r * 65 + c + 1];
    sv.z = scLb[r * 65 + c + 2]; sv.w = scLb[r * 65 + c + 3];
    *(float4*)&out[(g0 + r) * 64 + c]           = zv;
    *(float4*)&out[2097152 + (g0 + r) * 64 + c] = mv;
    *(float4*)&out[4194304 + (g0 + r) * 64 + c] = sv;
  }
}

extern "C" void kernel_launch(void* const* d_in, const int* in_sizes, int n_in,
                              void* d_out, int out_size, void* d_ws, size_t ws_size,
                              hipStream_t stream) {
  (void)in_sizes; (void)n_in; (void)out_size; (void)ws_size;
  const float* context = (const float*)d_in[0];
  const float* eps     = (const float*)d_in[1];
  const float* W1      = (const float*)d_in[2];
  const float* Wc      = (const float*)d_in[3];
  const float* b1      = (const float*)d_in[4];
  const float* W2      = (const float*)d_in[5];
  const float* b2      = (const float*)d_in[6];
  const float* W3      = (const float*)d_in[7];
  const float* b3      = (const float*)d_in[8];
  float* out = (float*)d_out;

  // ws: ctxp f32[2048*512] | mw1s f32[64*512] | b2s f32[512] | mw2f u16[262144] | mw3b u16[65536]
  float* ws   = (float*)d_ws;
  float* ctxp = ws;
  float* mw1s = ctxp + 2048 * 512;
  float* b2s  = mw1s + 64 * 512;
  u16*   mw2f = (u16*)(b2s + 512);
  u16*   mw3b = mw2f + 262144;

  prep_w<<<1410, 256, 0, stream>>>(W1, W2, b2, W3, mw1s, mw2f, mw3b, b2s);
  prep_ctx<<<dim3(2048, 2), 256, 0, stream>>>(context, Wc, b1, ctxp);
  made_main<<<1024, TPB, 0, stream>>>(eps, b3, ctxp, mw1s, mw3b, b2s, mw2f, out);
}

// Round 13
// 760.227 us; speedup vs baseline: 2.6345x; 1.0907x over previous
//
#include <hip/hip_runtime.h>
#include <hip/hip_bf16.h>

// D=64, H=512, B=2048, S=16, C=256. Rows = 32768 independent samples, 64 AR steps.
#define ROWS 32      // rows per block
#define TPB 512      // 8 waves; 2 blocks/CU

typedef unsigned short u16;
typedef __attribute__((ext_vector_type(8))) short bf16x8;
typedef __attribute__((ext_vector_type(16))) float f32x16;

__device__ __forceinline__ int deg_of_sorted(int i) {
  return (i < 72) ? (i / 9 + 1) : ((i - 8) / 8 + 1);
}
__device__ __forceinline__ int perm_of_sorted(int i) {
  int g, k;
  if (i < 72) { g = i / 9 + 1; k = i % 9; }
  else        { g = (i - 8) / 8 + 1; k = (i - 8) % 8; }
  return (g - 1) + 63 * k;
}
__device__ __forceinline__ int cum_deg(int d) {
  return (d <= 0) ? 0 : ((d <= 8) ? 9 * d : 8 * d + 8);
}
__device__ __forceinline__ u16 f2bfu(float x) {
  return __builtin_bit_cast(u16, __float2bfloat16(x));
}
__device__ __forceinline__ float softplus_f(float x) {
  return fmaxf(x, 0.f) + log1pf(expf(-fabsf(x)));
}

// ---------------- prep: permuted/masked weights ----------------
__global__ __launch_bounds__(256) void prep_w(
    const float* __restrict__ W1, const float* __restrict__ W2,
    const float* __restrict__ b2, const float* __restrict__ W3,
    float* __restrict__ mw1s, u16* __restrict__ mw2f,
    float* __restrict__ mw3f, float* __restrict__ b2s) {
  int idx = blockIdx.x * 256 + threadIdx.x;
  if (idx < 262144) {  // MW2 sorted+masked, MFMA fragment layout [(k>>3)][n][k&7]
    int kb = idx >> 12, n = (idx >> 3) & 511, kk = idx & 7;
    int k = kb * 8 + kk;
    float v = (deg_of_sorted(k) <= deg_of_sorted(n))
                  ? W2[perm_of_sorted(k) * 512 + perm_of_sorted(n)] : 0.f;
    mw2f[idx] = f2bfu(v);
    return;
  }
  idx -= 262144;
  if (idx < 32768) {   // MW1 sorted+masked rows d, cols sorted j (f32)
    int d = idx >> 9, j = idx & 511;
    mw1s[idx] = (deg_of_sorted(j) >= d + 1) ? W1[d * 512 + perm_of_sorted(j)] : 0.f;
    return;
  }
  idx -= 32768;
  if (idx < 65536) {   // MW3 transposed f32: [out col c(128)][sorted j(512)]
    int c = idx >> 9, j = idx & 511;
    mw3f[idx] = (deg_of_sorted(j) <= (c & 63)) ? W3[perm_of_sorted(j) * 128 + c] : 0.f;
    return;
  }
  idx -= 65536;
  if (idx < 512) b2s[idx] = b2[perm_of_sorted(idx)];
}

__global__ __launch_bounds__(256) void prep_ctx(
    const float* __restrict__ context, const float* __restrict__ Wc,
    const float* __restrict__ b1, float* __restrict__ ctxp) {
  __shared__ float cs[256];
  const int b = blockIdx.x;
  const int j = blockIdx.y * 256 + threadIdx.x;
  cs[threadIdx.x] = context[b * 256 + threadIdx.x];
  __syncthreads();
  const int pj = perm_of_sorted(j);
  float acc = b1[pj];
  #pragma unroll 4
  for (int c = 0; c < 256; ++c) acc += cs[c] * Wc[c * 512 + pj];
  ctxp[b * 512 + j] = acc;
}

// ---- main: persistent TRANSPOSED layer-2 acc (rows in lanes); per-lane layer-3 dot ----
__global__ __launch_bounds__(TPB, 4) void made_main(
    const float* __restrict__ eps, const float* __restrict__ b3,
    const float* __restrict__ ctxp, const float* __restrict__ mw1s,
    const float* __restrict__ mw3f, const float* __restrict__ b2sg,
    const u16* __restrict__ mw2f, float* __restrict__ out) {
  __shared__ __align__(16) u16   dbuf[2][32][32];    //  4096 B delta h1 (double-buffered)
  __shared__ __align__(16) float part2mu[32 * 9];    //  1152 B
  __shared__ __align__(16) float part2sc[32 * 9];    //  1152 B
  __shared__ __align__(16) float w1s[512];           //  2048 B staged w1 row d
  __shared__ __align__(16) float w3fs[2][2][512];    //  8192 B staged w3 rows (dbuffered)
  __shared__ __align__(16) float b3s[128];           //   512 B
  __shared__ __align__(16) float epsall[ROWS * 65];  //  8320 B
  __shared__ __align__(16) float zLb[ROWS * 65];     //  8320 B
  __shared__ __align__(16) float muLb[ROWS * 65];    //  8320 B
  __shared__ __align__(16) float scLb[ROWS * 65];    //  8320 B
  // total ~50 KB -> 2 blocks/CU

  const int tid  = threadIdx.x;
  const int lane = tid & 63;
  const int wave = tid >> 6;               // 0..7
  const int g0   = blockIdx.x * ROWS;
  const int b0   = g0 & 2047;

  // a1 ownership: row rA = tid&31, cols [jA, jA+32)
  const int rA = tid & 31;
  const int jA = (tid >> 5) << 5;
  float a1r[32];
  #pragma unroll
  for (int t = 0; t < 8; ++t) {
    *(float4*)&a1r[t * 4] = *(const float4*)&ctxp[(b0 + rA) * 512 + jA + t * 4];
  }

  // init LDS: zero dbuf, b3, eps, prologue w3fs[0] (d=0 rows c=0,64)
  ((unsigned*)dbuf)[tid] = 0u;
  ((unsigned*)dbuf)[tid + 512] = 0u;
  if (tid < 128) b3s[tid] = b3[tid];
  {
    int r = tid >> 4, c = (tid & 15) * 4;
    float4 ev = *(const float4*)&eps[(g0 + r) * 64 + c];
    epsall[r * 65 + c + 0] = ev.x;
    epsall[r * 65 + c + 1] = ev.y;
    epsall[r * 65 + c + 2] = ev.z;
    epsall[r * 65 + c + 3] = ev.w;
  }
  if (tid < 256) {
    int c_sel = tid >> 7, j0 = (tid & 127) * 4;
    *(float4*)&w3fs[0][c_sel][j0] = *(const float4*)&mw3f[(c_sel * 64) * 512 + j0];
  }
  __syncthreads();

  const int m  = lane & 31;   // for MFMA: A row (w2 col n) AND B col (h2 row r)
  const int kq = lane >> 5;   // k-half
  const int jt0 = wave;       // balanced pair per wave
  const int jt1 = 15 - wave;
  const u16* bLane = mw2f + ((kq * 512 + m) << 3);
  const u16* bp0   = bLane + jt0 * 256;
  const u16* bp1   = bLane + jt1 * 256;
  const int ke0full = cum_deg(deg_of_sorted(jt0 * 32 + 31));
  const int ke1full = cum_deg(deg_of_sorted(jt1 * 32 + 31));

  // persistent transposed layer-2 acc: lane = h2 ROW r(=m), regs = cols n_i.
  // bias folded into init (per-reg col bias).
  f32x16 acc0, acc1;
  #pragma unroll
  for (int i = 0; i < 16; ++i) {
    const int ni = (i & 3) + 8 * (i >> 2) + 4 * kq;
    acc0[i] = b2sg[jt0 * 32 + ni];
    acc1[i] = b2sg[jt1 * 32 + ni];
  }

  for (int d = 0; d < 64; ++d) {
    const int Cd    = cum_deg(d);
    const int Cnext = cum_deg(d + 1);
    const int Cprev = cum_deg(d - 1);       // d=0 -> 0
    const int cb    = d & 1;                // delta buffer read this step
    const int nb    = cb ^ 1;               // delta buffer written for next step

    // --- stage-issue: w1 row d (for C), w3 rows for step d+1
    float4 w1stg;
    if (tid < 128) w1stg = *(const float4*)&mw1s[d * 512 + tid * 4];
    float4 w3stg;
    int c_sel = 0, j0 = 0;
    if (tid >= 128 && tid < 384 && d < 63) {
      int t2 = tid - 128;
      c_sel = t2 >> 7; j0 = (t2 & 127) * 4;
      w3stg = *(const float4*)&mw3f[(c_sel * 64 + d + 1) * 512 + j0];
    }

    // --- Phase A: delta MFMA (swapped operands -> transposed acc)
    if (d > 0) {
      const int kb  = Cprev >> 4;
      const int nks = ((Cd - 1) >> 4) - kb + 1;    // 1 or 2
      #pragma unroll 2
      for (int t = 0; t < nks; ++t) {
        const int ks = kb + t;
        bf16x8 dF = *(const bf16x8*)((const u16*)&dbuf[cb][m][0] + t * 16 + kq * 8);
        if (ke0full > ks * 16) {
          bf16x8 wA = *(const bf16x8*)(bp0 + ks * 8192);
          acc0 = __builtin_amdgcn_mfma_f32_32x32x16_bf16(wA, dF, acc0, 0, 0, 0);
        }
        if (ke1full > ks * 16) {
          bf16x8 wB = *(const bf16x8*)(bp1 + ks * 8192);
          acc1 = __builtin_amdgcn_mfma_f32_32x32x16_bf16(wB, dF, acc1, 0, 0, 0);
        }
      }
    }

    // --- Phase B: per-lane layer-3 dot over regs (w3 uniform LDS reads, broadcast)
    {
      const float* w3c = &w3fs[cb][0][0];
      float pmu = 0.f, psc = 0.f;
      #pragma unroll
      for (int g = 0; g < 4; ++g) {
        const int n0 = jt0 * 32 + 8 * g + 4 * kq;
        const int n1 = jt1 * 32 + 8 * g + 4 * kq;
        const float4 m0 = *(const float4*)&w3c[n0];
        const float4 s0 = *(const float4*)&w3c[512 + n0];
        const float4 m1 = *(const float4*)&w3c[n1];
        const float4 s1 = *(const float4*)&w3c[512 + n1];
        float h00 = fmaxf(acc0[4 * g + 0], 0.f), h10 = fmaxf(acc1[4 * g + 0], 0.f);
        float h01 = fmaxf(acc0[4 * g + 1], 0.f), h11 = fmaxf(acc1[4 * g + 1], 0.f);
        float h02 = fmaxf(acc0[4 * g + 2], 0.f), h12 = fmaxf(acc1[4 * g + 2], 0.f);
        float h03 = fmaxf(acc0[4 * g + 3], 0.f), h13 = fmaxf(acc1[4 * g + 3], 0.f);
        pmu += h00 * m0.x + h10 * m1.x;  psc += h00 * s0.x + h10 * s1.x;
        pmu += h01 * m0.y + h11 * m1.y;  psc += h01 * s0.y + h11 * s1.y;
        pmu += h02 * m0.z + h12 * m1.z;  psc += h02 * s0.z + h12 * s1.z;
        pmu += h03 * m0.w + h13 * m1.w;  psc += h03 * s0.w + h13 * s1.w;
      }
      pmu += __shfl_xor(pmu, 32);
      psc += __shfl_xor(psc, 32);
      if (kq == 0) {
        part2mu[m * 9 + wave] = pmu;
        part2sc[m * 9 + wave] = psc;
      }
    }

    // zero next delta buffer (last read of it was >=1 barrier ago)
    ((unsigned*)dbuf[nb])[tid] = 0u;

    // stage-write (latency hidden under phase A/B)
    if (tid < 128) *(float4*)&w1s[tid * 4] = w1stg;
    else if (tid < 384 && d < 63) *(float4*)&w3fs[nb][c_sel][j0] = w3stg;
    __syncthreads();

    // --- B2 (replicated all threads): sum 8 wave partials, softplus, sample
    float msum = b3s[d], ssum = b3s[64 + d];
    #pragma unroll
    for (int w = 0; w < 8; ++w) {
      msum += part2mu[rA * 9 + w];
      ssum += part2sc[rA * 9 + w];
    }
    const float mu = msum;
    const float sc = softplus_f(ssum);
    const float z  = fmaf(sc, epsall[rA * 65 + d], mu);
    if (tid < 32) {            // one writer per row; conflict-free (stride 65)
      zLb[rA * 65 + d]  = z;
      muLb[rA * 65 + d] = mu;
      scLb[rA * 65 + d] = sc;
    }

    // --- Phase C: rank-1 a1 update on owned slice + freeze new cols into next delta
    if (jA + 31 >= Cd) {
      const int kbw = Cd >> 4;               // next step's delta window base
      #pragma unroll
      for (int i = 0; i < 32; ++i) {
        int j = jA + i;
        if (j >= Cd) a1r[i] += z * w1s[j];
      }
      if (jA < Cnext) {
        #pragma unroll
        for (int i = 0; i < 32; ++i) {
          int j = jA + i;
          if (j >= Cd && j < Cnext) {
            dbuf[nb][rA][j - kbw * 16] = f2bfu(fmaxf(a1r[i], 0.f));
          }
        }
      }
    }
    __syncthreads();
  }

  // --- final coalesced flush of z/mu/sc
  {
    const int r = tid >> 4, c = (tid & 15) * 4;
    float4 zv, mv, sv;
    zv.x = zLb[r * 65 + c + 0]; zv.y = zLb[r * 65 + c + 1];
    zv.z = zLb[r * 65 + c + 2]; zv.w = zLb[r * 65 + c + 3];
    mv.x = muLb[r * 65 + c + 0]; mv.y = muLb[r * 65 + c + 1];
    mv.z = muLb[r * 65 + c + 2]; mv.w = muLb[r * 65 + c + 3];
    sv.x = scLb[r * 65 + c + 0]; sv.y = scLb[r * 65 + c + 1];
    sv.z = scLb[r * 65 + c + 2]; sv.w = scLb[r * 65 + c + 3];
    *(float4*)&out[(g0 + r) * 64 + c]           = zv;
    *(float4*)&out[2097152 + (g0 + r) * 64 + c] = mv;
    *(float4*)&out[4194304 + (g0 + r) * 64 + c] = sv;
  }
}

extern "C" void kernel_launch(void* const* d_in, const int* in_sizes, int n_in,
                              void* d_out, int out_size, void* d_ws, size_t ws_size,
                              hipStream_t stream) {
  (void)in_sizes; (void)n_in; (void)out_size; (void)ws_size;
  const float* context = (const float*)d_in[0];
  const float* eps     = (const float*)d_in[1];
  const float* W1      = (const float*)d_in[2];
  const float* Wc      = (const float*)d_in[3];
  const float* b1      = (const float*)d_in[4];
  const float* W2      = (const float*)d_in[5];
  const float* b2      = (const float*)d_in[6];
  const float* W3      = (const float*)d_in[7];
  const float* b3      = (const float*)d_in[8];
  float* out = (float*)d_out;

  // ws: ctxp f32[1048576] | mw1s f32[32768] | b2s f32[512] | mw3f f32[65536] | mw2f u16[262144]
  float* ws   = (float*)d_ws;
  float* ctxp = ws;
  float* mw1s = ctxp + 1048576;
  float* b2s  = mw1s + 32768;
  float* mw3f = b2s + 512;
  u16*   mw2f = (u16*)(mw3f + 65536);

  prep_w<<<1410, 256, 0, stream>>>(W1, W2, b2, W3, mw1s, mw2f, mw3f, b2s);
  prep_ctx<<<dim3(2048, 2), 256, 0, stream>>>(context, Wc, b1, ctxp);
  made_main<<<1024, TPB, 0, stream>>>(eps, b3, ctxp, mw1s, mw3f, b2s, mw2f, out);
}

// Round 14
// 650.472 us; speedup vs baseline: 3.0791x; 1.1687x over previous
//
#include <hip/hip_runtime.h>
#include <hip/hip_bf16.h>

// D=64, H=512, B=2048, S=16, C=256. Rows = 32768 independent samples, 64 AR steps.
#define ROWS 32      // rows per block
#define TPB 512      // 8 waves; 2 blocks/CU

typedef unsigned short u16;
typedef __attribute__((ext_vector_type(8))) short bf16x8;
typedef __attribute__((ext_vector_type(16))) float f32x16;

__device__ __forceinline__ int deg_of_sorted(int i) {
  return (i < 72) ? (i / 9 + 1) : ((i - 8) / 8 + 1);
}
__device__ __forceinline__ int perm_of_sorted(int i) {
  int g, k;
  if (i < 72) { g = i / 9 + 1; k = i % 9; }
  else        { g = (i - 8) / 8 + 1; k = (i - 8) % 8; }
  return (g - 1) + 63 * k;
}
__device__ __forceinline__ int cum_deg(int d) {
  return (d <= 0) ? 0 : ((d <= 8) ? 9 * d : 8 * d + 8);
}
__device__ __forceinline__ u16 f2bfu(float x) {
  return __builtin_bit_cast(u16, __float2bfloat16(x));
}
__device__ __forceinline__ float softplus_f(float x) {
  return fmaxf(x, 0.f) + log1pf(expf(-fabsf(x)));
}

// ---------------- prep: permuted/masked weights ----------------
__global__ __launch_bounds__(256) void prep_w(
    const float* __restrict__ W1, const float* __restrict__ W2,
    const float* __restrict__ b2, const float* __restrict__ W3,
    float* __restrict__ mw1s, u16* __restrict__ mw2f,
    float* __restrict__ mw3f, float* __restrict__ b2s) {
  int idx = blockIdx.x * 256 + threadIdx.x;
  if (idx < 262144) {  // MW2 sorted+masked, MFMA fragment layout [(k>>3)][n][k&7]
    int kb = idx >> 12, n = (idx >> 3) & 511, kk = idx & 7;
    int k = kb * 8 + kk;
    float v = (deg_of_sorted(k) <= deg_of_sorted(n))
                  ? W2[perm_of_sorted(k) * 512 + perm_of_sorted(n)] : 0.f;
    mw2f[idx] = f2bfu(v);
    return;
  }
  idx -= 262144;
  if (idx < 32768) {   // MW1 sorted+masked rows d, cols sorted j (f32)
    int d = idx >> 9, j = idx & 511;
    mw1s[idx] = (deg_of_sorted(j) >= d + 1) ? W1[d * 512 + perm_of_sorted(j)] : 0.f;
    return;
  }
  idx -= 32768;
  if (idx < 65536) {   // MW3 transposed f32: [out col c(128)][sorted j(512)]
    int c = idx >> 9, j = idx & 511;
    mw3f[idx] = (deg_of_sorted(j) <= (c & 63)) ? W3[perm_of_sorted(j) * 128 + c] : 0.f;
    return;
  }
  idx -= 65536;
  if (idx < 512) b2s[idx] = b2[perm_of_sorted(idx)];
}

// ctx_proj with b-row reuse: 16 rows per block, Wc row read once per block per c
__global__ __launch_bounds__(512) void prep_ctx(
    const float* __restrict__ context, const float* __restrict__ Wc,
    const float* __restrict__ b1, float* __restrict__ ctxp) {
  __shared__ float cs[16][257];
  const int tid = threadIdx.x;
  const int b0  = blockIdx.x * 16;
  for (int i = tid; i < 16 * 256; i += 512) {
    int r = i >> 8, c = i & 255;
    cs[r][c] = context[(b0 + r) * 256 + c];
  }
  __syncthreads();
  const int j  = tid;
  const int pj = perm_of_sorted(j);
  float acc[16];
  const float bv = b1[pj];
  #pragma unroll
  for (int r = 0; r < 16; ++r) acc[r] = bv;
  for (int c = 0; c < 256; c += 4) {
    float w0 = Wc[(c + 0) * 512 + pj];
    float w1 = Wc[(c + 1) * 512 + pj];
    float w2 = Wc[(c + 2) * 512 + pj];
    float w3 = Wc[(c + 3) * 512 + pj];
    #pragma unroll
    for (int r = 0; r < 16; ++r) {
      acc[r] += cs[r][c + 0] * w0 + cs[r][c + 1] * w1 +
                cs[r][c + 2] * w2 + cs[r][c + 3] * w3;
    }
  }
  #pragma unroll
  for (int r = 0; r < 16; ++r) ctxp[(b0 + r) * 512 + j] = acc[r];
}

// ---- main: persistent TRANSPOSED layer-2 acc; gated per-lane layer-3 dot ----
__global__ __launch_bounds__(TPB, 4) void made_main(
    const float* __restrict__ eps, const float* __restrict__ b3,
    const float* __restrict__ ctxp, const float* __restrict__ mw1s,
    const float* __restrict__ mw3f, const float* __restrict__ b2sg,
    const u16* __restrict__ mw2f, float* __restrict__ out) {
  __shared__ __align__(16) u16   dbuf[2][32][32];    //  4096 B delta h1 (double-buffered)
  __shared__ __align__(16) float part2mu[9 * 33];    //  1188 B [wave][row]
  __shared__ __align__(16) float part2sc[9 * 33];    //  1188 B
  __shared__ __align__(16) float w1s[512];           //  2048 B staged w1 row d
  __shared__ __align__(16) float w3fs[2][2][512];    //  8192 B staged w3 rows (dbuffered)
  __shared__ __align__(16) float b3s[128];           //   512 B
  __shared__ __align__(16) float epsall[ROWS * 65];  //  8320 B
  __shared__ __align__(16) float zLb[ROWS * 65];     //  8320 B
  __shared__ __align__(16) float muLb[ROWS * 65];    //  8320 B
  __shared__ __align__(16) float scLb[ROWS * 65];    //  8320 B

  const int tid  = threadIdx.x;
  const int lane = tid & 63;
  const int wave = tid >> 6;               // 0..7
  const int g0   = blockIdx.x * ROWS;
  const int b0   = g0 & 2047;

  // a1 ownership: row rA = tid&31, cols [jA, jA+32)
  const int rA = tid & 31;
  const int jA = (tid >> 5) << 5;
  float a1r[32];
  #pragma unroll
  for (int t = 0; t < 8; ++t) {
    *(float4*)&a1r[t * 4] = *(const float4*)&ctxp[(b0 + rA) * 512 + jA + t * 4];
  }

  // init LDS: zero dbuf, b3, eps, prologue w3fs[0]
  ((unsigned*)dbuf)[tid] = 0u;
  ((unsigned*)dbuf)[tid + 512] = 0u;
  if (tid < 128) b3s[tid] = b3[tid];
  {
    int r = tid >> 4, c = (tid & 15) * 4;
    float4 ev = *(const float4*)&eps[(g0 + r) * 64 + c];
    epsall[r * 65 + c + 0] = ev.x;
    epsall[r * 65 + c + 1] = ev.y;
    epsall[r * 65 + c + 2] = ev.z;
    epsall[r * 65 + c + 3] = ev.w;
  }
  if (tid < 256) {
    int c_sel = tid >> 7, j0 = (tid & 127) * 4;
    *(float4*)&w3fs[0][c_sel][j0] = *(const float4*)&mw3f[(c_sel * 64) * 512 + j0];
  }
  __syncthreads();

  const int m  = lane & 31;   // MFMA: A row (w2 col n) AND B col (h2 row r)
  const int kq = lane >> 5;   // k-half
  const int jt0 = wave;       // balanced pair per wave
  const int jt1 = 15 - wave;
  const u16* bLane = mw2f + ((kq * 512 + m) << 3);
  const u16* bp0   = bLane + jt0 * 256;
  const u16* bp1   = bLane + jt1 * 256;
  const int ke0full = cum_deg(deg_of_sorted(jt0 * 32 + 31));
  const int ke1full = cum_deg(deg_of_sorted(jt1 * 32 + 31));

  // persistent transposed layer-2 acc: lane = h2 ROW r(=m), regs = cols n_i (bias-init)
  f32x16 acc0, acc1;
  #pragma unroll
  for (int i = 0; i < 16; ++i) {
    const int ni = (i & 3) + 8 * (i >> 2) + 4 * kq;
    acc0[i] = b2sg[jt0 * 32 + ni];
    acc1[i] = b2sg[jt1 * 32 + ni];
  }

  for (int d = 0; d < 64; ++d) {
    const int Cd    = cum_deg(d);
    const int Cnext = cum_deg(d + 1);
    const int Cprev = cum_deg(d - 1);       // d=0 -> 0
    const int cb    = d & 1;
    const int nb    = cb ^ 1;

    // --- stage-issue: w1 row d, w3 rows for step d+1
    float4 w1stg;
    if (tid < 128) w1stg = *(const float4*)&mw1s[d * 512 + tid * 4];
    float4 w3stg;
    int c_sel = 0, j0 = 0;
    if (tid >= 128 && tid < 384 && d < 63) {
      int t2 = tid - 128;
      c_sel = t2 >> 7; j0 = (t2 & 127) * 4;
      w3stg = *(const float4*)&mw3f[(c_sel * 64 + d + 1) * 512 + j0];
    }

    // --- Phase A: delta MFMA (swapped operands -> transposed acc)
    if (d > 0) {
      const int kb  = Cprev >> 4;
      const int nks = ((Cd - 1) >> 4) - kb + 1;    // 1 or 2
      #pragma unroll 2
      for (int t = 0; t < nks; ++t) {
        const int ks = kb + t;
        bf16x8 dF = *(const bf16x8*)((const u16*)&dbuf[cb][m][0] + t * 16 + kq * 8);
        if (ke0full > ks * 16) {
          bf16x8 wA = *(const bf16x8*)(bp0 + ks * 8192);
          acc0 = __builtin_amdgcn_mfma_f32_32x32x16_bf16(wA, dF, acc0, 0, 0, 0);
        }
        if (ke1full > ks * 16) {
          bf16x8 wB = *(const bf16x8*)(bp1 + ks * 8192);
          acc1 = __builtin_amdgcn_mfma_f32_32x32x16_bf16(wB, dF, acc1, 0, 0, 0);
        }
      }
    }

    // --- Phase B: gated per-lane layer-3 dot (wave-uniform gates, no divergence)
    {
      const float* w3c = &w3fs[cb][0][0];
      float pmu = 0.f, psc = 0.f;
      if (jt0 * 32 < Cd) {
        #pragma unroll
        for (int g = 0; g < 4; ++g) {
          const int n0 = jt0 * 32 + 8 * g + 4 * kq;
          const float4 m0 = *(const float4*)&w3c[n0];
          const float4 s0 = *(const float4*)&w3c[512 + n0];
          float h0 = fmaxf(acc0[4 * g + 0], 0.f);
          float h1 = fmaxf(acc0[4 * g + 1], 0.f);
          float h2 = fmaxf(acc0[4 * g + 2], 0.f);
          float h3 = fmaxf(acc0[4 * g + 3], 0.f);
          pmu += h0 * m0.x + h1 * m0.y + h2 * m0.z + h3 * m0.w;
          psc += h0 * s0.x + h1 * s0.y + h2 * s0.z + h3 * s0.w;
        }
      }
      if (jt1 * 32 < Cd) {
        #pragma unroll
        for (int g = 0; g < 4; ++g) {
          const int n1 = jt1 * 32 + 8 * g + 4 * kq;
          const float4 m1 = *(const float4*)&w3c[n1];
          const float4 s1 = *(const float4*)&w3c[512 + n1];
          float h0 = fmaxf(acc1[4 * g + 0], 0.f);
          float h1 = fmaxf(acc1[4 * g + 1], 0.f);
          float h2 = fmaxf(acc1[4 * g + 2], 0.f);
          float h3 = fmaxf(acc1[4 * g + 3], 0.f);
          pmu += h0 * m1.x + h1 * m1.y + h2 * m1.z + h3 * m1.w;
          psc += h0 * s1.x + h1 * s1.y + h2 * s1.z + h3 * s1.w;
        }
      }
      pmu += __shfl_xor(pmu, 32);
      psc += __shfl_xor(psc, 32);
      if (kq == 0) {
        part2mu[wave * 33 + m] = pmu;
        part2sc[wave * 33 + m] = psc;
      }
    }

    // zero next delta buffer (last read of it was >=1 barrier ago)
    ((unsigned*)dbuf[nb])[tid] = 0u;

    // stage-write (latency hidden under phase A/B)
    if (tid < 128) *(float4*)&w1s[tid * 4] = w1stg;
    else if (tid < 384 && d < 63) *(float4*)&w3fs[nb][c_sel][j0] = w3stg;
    __syncthreads();

    // --- B2 (replicated): sum 8 wave partials, softplus, sample
    float msum = b3s[d], ssum = b3s[64 + d];
    #pragma unroll
    for (int w = 0; w < 8; ++w) {
      msum += part2mu[w * 33 + rA];
      ssum += part2sc[w * 33 + rA];
    }
    const float mu = msum;
    const float sc = softplus_f(ssum);
    const float z  = fmaf(sc, epsall[rA * 65 + d], mu);
    if (tid < 32) {
      zLb[rA * 65 + d]  = z;
      muLb[rA * 65 + d] = mu;
      scLb[rA * 65 + d] = sc;
    }

    // --- Phase C: rank-1 a1 update on owned slice + freeze new cols into next delta
    if (jA + 31 >= Cd) {
      const int kbw = Cd >> 4;
      #pragma unroll
      for (int i = 0; i < 32; ++i) {
        int j = jA + i;
        if (j >= Cd) a1r[i] += z * w1s[j];
      }
      if (jA < Cnext) {
        #pragma unroll
        for (int i = 0; i < 32; ++i) {
          int j = jA + i;
          if (j >= Cd && j < Cnext) {
            dbuf[nb][rA][j - kbw * 16] = f2bfu(fmaxf(a1r[i], 0.f));
          }
        }
      }
    }
    __syncthreads();
  }

  // --- final coalesced flush of z/mu/sc
  {
    const int r = tid >> 4, c = (tid & 15) * 4;
    float4 zv, mv, sv;
    zv.x = zLb[r * 65 + c + 0]; zv.y = zLb[r * 65 + c + 1];
    zv.z = zLb[r * 65 + c + 2]; zv.w = zLb[r * 65 + c + 3];
    mv.x = muLb[r * 65 + c + 0]; mv.y = muLb[r * 65 + c + 1];
    mv.z = muLb[r * 65 + c + 2]; mv.w = muLb[r * 65 + c + 3];
    sv.x = scLb[r * 65 + c + 0]; sv.y = scLb[r * 65 + c + 1];
    sv.z = scLb[r * 65 + c + 2]; sv.w = scLb[r * 65 + c + 3];
    *(float4*)&out[(g0 + r) * 64 + c]           = zv;
    *(float4*)&out[2097152 + (g0 + r) * 64 + c] = mv;
    *(float4*)&out[4194304 + (g0 + r) * 64 + c] = sv;
  }
}

extern "C" void kernel_launch(void* const* d_in, const int* in_sizes, int n_in,
                              void* d_out, int out_size, void* d_ws, size_t ws_size,
                              hipStream_t stream) {
  (void)in_sizes; (void)n_in; (void)out_size; (void)ws_size;
  const float* context = (const float*)d_in[0];
  const float* eps     = (const float*)d_in[1];
  const float* W1      = (const float*)d_in[2];
  const float* Wc      = (const float*)d_in[3];
  const float* b1      = (const float*)d_in[4];
  const float* W2      = (const float*)d_in[5];
  const float* b2      = (const float*)d_in[6];
  const float* W3      = (const float*)d_in[7];
  const float* b3      = (const float*)d_in[8];
  float* out = (float*)d_out;

  // ws: ctxp f32[1048576] | mw1s f32[32768] | b2s f32[512] | mw3f f32[65536] | mw2f u16[262144]
  float* ws   = (float*)d_ws;
  float* ctxp = ws;
  float* mw1s = ctxp + 1048576;
  float* b2s  = mw1s + 32768;
  float* mw3f = b2s + 512;
  u16*   mw2f = (u16*)(mw3f + 65536);

  prep_w<<<1410, 256, 0, stream>>>(W1, W2, b2, W3, mw1s, mw2f, mw3f, b2s);
  prep_ctx<<<128, 512, 0, stream>>>(context, Wc, b1, ctxp);
  made_main<<<1024, TPB, 0, stream>>>(eps, b3, ctxp, mw1s, mw3f, b2s, mw2f, out);
}